// Round 1
// baseline (2603.719 us; speedup 1.0000x reference)
//
#include <hip/hip_runtime.h>

#define NN 32768
#define EE 262144

// ---- ordered-uint encoding for atomic float max (handles negatives) ----
static __device__ __forceinline__ unsigned enc_f(float x){
  unsigned u = __float_as_uint(x);
  return (u & 0x80000000u) ? ~u : (u | 0x80000000u);
}
static __device__ __forceinline__ float dec_f(unsigned u){
  return __uint_as_float((u & 0x80000000u) ? (u ^ 0x80000000u) : ~u);
}
static __device__ __forceinline__ float sigm(float x){
  return 1.0f / (1.0f + __expf(-x));
}

// ---------------- node pass: o3-layernorm + src/dst linears ----------------
__global__ __launch_bounds__(256) void k_node(
    const float* __restrict__ node,
    const float* __restrict__ Wss, const float* __restrict__ Wsv,
    const float* __restrict__ Wds, const float* __restrict__ Wdv,
    float* __restrict__ ss, float* __restrict__ ds,
    float* __restrict__ sv, float* __restrict__ dv)
{
  int n = blockIdx.x * 256 + threadIdx.x;
  if (n >= NN) return;
  const float4* row = reinterpret_cast<const float4*>(node + (size_t)n * 80);
  float s[32], v[48];
#pragma unroll
  for (int i = 0; i < 8; ++i){
    float4 t = row[i];
    s[i*4+0]=t.x; s[i*4+1]=t.y; s[i*4+2]=t.z; s[i*4+3]=t.w;
  }
#pragma unroll
  for (int i = 0; i < 12; ++i){
    float4 t = row[8+i];
    v[i*4+0]=t.x; v[i*4+1]=t.y; v[i*4+2]=t.z; v[i*4+3]=t.w;
  }
  float mean = 0.f;
#pragma unroll
  for (int i=0;i<32;++i) mean += s[i];
  mean *= (1.0f/32.0f);
  float var = 0.f;
#pragma unroll
  for (int i=0;i<32;++i){ float d0 = s[i]-mean; var += d0*d0; }
  var *= (1.0f/32.0f);
  float sinv = rsqrtf(var + 1e-5f);
#pragma unroll
  for (int i=0;i<32;++i) s[i] = (s[i]-mean)*sinv;
  float n2 = 0.f;
#pragma unroll
  for (int i=0;i<48;++i) n2 += v[i]*v[i];
  n2 *= (1.0f/16.0f);
  float vinv = rsqrtf(n2 + 1e-5f);
#pragma unroll
  for (int i=0;i<48;++i) v[i] *= vinv;

  float* ssr = ss + (size_t)n*32;
  float* dsr = ds + (size_t)n*32;
#pragma unroll 1
  for (int d=0; d<32; ++d){
    float a=0.f, b=0.f;
#pragma unroll
    for (int c=0;c<32;++c){ a += s[c]*Wss[c*32+d]; b += s[c]*Wds[c*32+d]; }
    ssr[d]=a; dsr[d]=b;
  }
  float* svr = sv + (size_t)n*48;
  float* dvr = dv + (size_t)n*48;
#pragma unroll 1
  for (int d=0; d<16; ++d){
#pragma unroll
    for (int x=0;x<3;++x){
      float a=0.f, b=0.f;
#pragma unroll
      for (int c=0;c<16;++c){ a += v[c*3+x]*Wsv[c*16+d]; b += v[c*3+x]*Wdv[c*16+d]; }
      svr[d*3+x]=a; dvr[d*3+x]=b;
    }
  }
}

// ------------- edge pass A: attention logits + segment max (atomic) --------
__global__ __launch_bounds__(256) void k_edgeA(
    const int* __restrict__ ei,
    const float* __restrict__ rbf, const float* __restrict__ rsh,
    const float* __restrict__ Wrbf, const float* __restrict__ Wa,
    const float* __restrict__ adot,
    const float* __restrict__ ss, const float* __restrict__ ds,
    const float* __restrict__ sv, const float* __restrict__ dv,
    float* __restrict__ logits, unsigned* __restrict__ menc)
{
  int e = blockIdx.x * 256 + threadIdx.x;
  if (e >= EE) return;
  int src = ei[e], dst = ei[EE + e];
  float r[16];
  { const float4* rp = reinterpret_cast<const float4*>(rbf + (size_t)e*16);
#pragma unroll
    for (int i=0;i<4;++i){ float4 t=rp[i]; r[i*4]=t.x; r[i*4+1]=t.y; r[i*4+2]=t.z; r[i*4+3]=t.w; } }
  float4 yv = reinterpret_cast<const float4*>(rsh)[e];
  const float y0=yv.x, y1x=yv.y, y1y=yv.z, y1z=yv.w;

  float ms[48];
  { const float4* ap = reinterpret_cast<const float4*>(ss + (size_t)src*32);
    const float4* bp = reinterpret_cast<const float4*>(ds + (size_t)dst*32);
    float s_[32];
#pragma unroll
    for (int i=0;i<8;++i){ float4 a=ap[i], b=bp[i];
      s_[i*4]=a.x+b.x; s_[i*4+1]=a.y+b.y; s_[i*4+2]=a.z+b.z; s_[i*4+3]=a.w+b.w; }
#pragma unroll
    for (int c=0;c<32;++c){
      float w=0.f;
#pragma unroll
      for (int j=0;j<16;++j) w += r[j]*Wrbf[j*112+c];
      ms[c] = w * s_[c] * y0;
    }
  }
  {
    const float4* ap = reinterpret_cast<const float4*>(sv + (size_t)src*48);
    const float4* bp = reinterpret_cast<const float4*>(dv + (size_t)dst*48);
    float v_[48];
#pragma unroll
    for (int i=0;i<12;++i){ float4 a=ap[i], b=bp[i];
      v_[i*4]=a.x+b.x; v_[i*4+1]=a.y+b.y; v_[i*4+2]=a.z+b.z; v_[i*4+3]=a.w+b.w; }
    const float is3 = 0.57735026918962576f;
#pragma unroll
    for (int k=0;k<16;++k){
      float w=0.f;
#pragma unroll
      for (int j=0;j<16;++j) w += r[j]*Wrbf[j*112+80+k];
      float dt = (v_[k*3]*y1x + v_[k*3+1]*y1y + v_[k*3+2]*y1z)*is3;
      ms[32+k] = w*dt;
    }
  }
#pragma unroll 1
  for (int h=0;h<4;++h){
    float acc=0.f;
#pragma unroll 1
    for (int j=0;j<16;++j){
      float t=0.f;
#pragma unroll
      for (int c=0;c<48;++c) t += ms[c]*Wa[c*64 + h*16 + j];
      t = (t > 0.f) ? t : 0.2f*t;
      acc += t * adot[h*16+j];
    }
    logits[(size_t)e*4+h] = acc;
    atomicMax(menc + ((size_t)dst*4+h), enc_f(acc));
  }
}

// ------------- edge pass B: softmax denominators ---------------------------
__global__ __launch_bounds__(256) void k_edgeB(
    const int* __restrict__ ei, const float* __restrict__ logits,
    const unsigned* __restrict__ menc, float* __restrict__ den)
{
  int e = blockIdx.x * 256 + threadIdx.x;
  if (e >= EE) return;
  int dst = ei[EE + e];
  float4 l4 = reinterpret_cast<const float4*>(logits)[e];
  float l[4] = {l4.x, l4.y, l4.z, l4.w};
#pragma unroll
  for (int h=0;h<4;++h){
    float mm = dec_f(menc[(size_t)dst*4+h]);
    atomicAdd(den + ((size_t)dst*4+h), __expf(l[h]-mm));
  }
}

// ------------- edge pass C: full value pipeline + weighted aggregation -----
__global__ __launch_bounds__(256) void k_edgeC(
    const int* __restrict__ ei,
    const float* __restrict__ rbf, const float* __restrict__ rsh,
    const float* __restrict__ Wrbf,
    const float* __restrict__ Wvals, const float* __restrict__ Wvalv,
    const float* __restrict__ Wg, const float* __restrict__ Wvls,
    const float* __restrict__ Wvlv, const float* __restrict__ w2,
    const float* __restrict__ ss, const float* __restrict__ ds,
    const float* __restrict__ sv, const float* __restrict__ dv,
    const float* __restrict__ logits, const unsigned* __restrict__ menc,
    const float* __restrict__ den, float* __restrict__ agg)
{
  int e = blockIdx.x * 256 + threadIdx.x;
  if (e >= EE) return;
  int src = ei[e], dst = ei[EE + e];

  float4 yv = reinterpret_cast<const float4*>(rsh)[e];
  const float y0=yv.x, y1_0=yv.y, y1_1=yv.z, y1_2=yv.w;

  // normalized attention weights (4 heads, kept as scalars: no runtime array idx)
  float a0,a1,a2,a3;
  {
    float4 l4 = reinterpret_cast<const float4*>(logits)[e];
    a0 = __expf(l4.x - dec_f(menc[(size_t)dst*4+0])) / den[(size_t)dst*4+0];
    a1 = __expf(l4.y - dec_f(menc[(size_t)dst*4+1])) / den[(size_t)dst*4+1];
    a2 = __expf(l4.z - dec_f(menc[(size_t)dst*4+2])) / den[(size_t)dst*4+2];
    a3 = __expf(l4.w - dec_f(menc[(size_t)dst*4+3])) / den[(size_t)dst*4+3];
  }

  float r[16];
  { const float4* rp = reinterpret_cast<const float4*>(rbf + (size_t)e*16);
#pragma unroll
    for (int i=0;i<4;++i){ float4 t=rp[i]; r[i*4]=t.x; r[i*4+1]=t.y; r[i*4+2]=t.z; r[i*4+3]=t.w; } }

  float s_[32];
  { const float4* ap = reinterpret_cast<const float4*>(ss + (size_t)src*32);
    const float4* bp = reinterpret_cast<const float4*>(ds + (size_t)dst*32);
#pragma unroll
    for (int i=0;i<8;++i){ float4 a=ap[i], b=bp[i];
      s_[i*4]=a.x+b.x; s_[i*4+1]=a.y+b.y; s_[i*4+2]=a.z+b.z; s_[i*4+3]=a.w+b.w; } }
  float v_[48];
  { const float4* ap = reinterpret_cast<const float4*>(sv + (size_t)src*48);
    const float4* bp = reinterpret_cast<const float4*>(dv + (size_t)dst*48);
#pragma unroll
    for (int i=0;i<12;++i){ float4 a=ap[i], b=bp[i];
      v_[i*4]=a.x+b.x; v_[i*4+1]=a.y+b.y; v_[i*4+2]=a.z+b.z; v_[i*4+3]=a.w+b.w; } }

  const float is3 = 0.57735026918962576f;
  const float is2 = 0.70710678118654752f;

  // recompute ms_ : [w_ss*s*y0 (32), w_vd*dot (16)]
  float ms[48];
#pragma unroll
  for (int c=0;c<32;++c){
    float w=0.f;
#pragma unroll
    for (int j=0;j<16;++j) w += r[j]*Wrbf[j*112+c];
    ms[c] = w * s_[c] * y0;
  }
#pragma unroll
  for (int k=0;k<16;++k){
    float w=0.f;
#pragma unroll
    for (int j=0;j<16;++j) w += r[j]*Wrbf[j*112+80+k];
    float dt = (v_[k*3]*y1_0 + v_[k*3+1]*y1_1 + v_[k*3+2]*y1_2)*is3;
    ms[32+k] = w*dt;
  }

  // vv = einsum(mv_, Wval_v) decomposed: rank-1 part (s*w_sv), v part, cross part
  float t_[32];
#pragma unroll
  for (int c=0;c<32;++c){
    float w=0.f;
#pragma unroll
    for (int j=0;j<16;++j) w += r[j]*Wrbf[j*112+32+c];
    t_[c] = w * s_[c];
  }
  float sa[16];
#pragma unroll
  for (int d=0;d<16;++d){
    float a=0.f;
#pragma unroll
    for (int c=0;c<32;++c) a += t_[c]*Wvalv[c*16+d];
    sa[d]=a;
  }
  float p[48], q[48];
#pragma unroll
  for (int k=0;k<16;++k){
    float wvs=0.f, wvc=0.f;
#pragma unroll
    for (int j=0;j<16;++j){ wvs += r[j]*Wrbf[j*112+64+k]; wvc += r[j]*Wrbf[j*112+96+k]; }
    float vx=v_[k*3], vy=v_[k*3+1], vz=v_[k*3+2];
    float u = wvs * y0;
    p[k*3]=u*vx; p[k*3+1]=u*vy; p[k*3+2]=u*vz;
    float cx=(vy*y1_2 - vz*y1_1)*is2;
    float cy=(vz*y1_0 - vx*y1_2)*is2;
    float cz=(vx*y1_1 - vy*y1_0)*is2;
    q[k*3]=wvc*cx; q[k*3+1]=wvc*cy; q[k*3+2]=wvc*cz;
  }
  float vv[48];
#pragma unroll
  for (int d=0;d<16;++d){
    float b0=sa[d]*y1_0, b1=sa[d]*y1_1, b2=sa[d]*y1_2;
#pragma unroll
    for (int k=0;k<16;++k){
      float wB = Wvalv[(32+k)*16+d];
      float wC = Wvalv[(48+k)*16+d];
      b0 += p[k*3+0]*wB + q[k*3+0]*wC;
      b1 += p[k*3+1]*wB + q[k*3+1]*wC;
      b2 += p[k*3+2]*wB + q[k*3+2]*wC;
    }
    vv[d*3]=b0; vv[d*3+1]=b1; vv[d*3+2]=b2;
  }

  // vs = ms_ @ Wval_s
  float vs[32];
#pragma unroll
  for (int d=0;d<32;++d){
    float a=0.f;
#pragma unroll
    for (int c=0;c<48;++c) a += ms[c]*Wvals[c*32+d];
    vs[d]=a;
  }
  // gating (gv from pre-silu vs), silu, gate vv
  float gv[16];
#pragma unroll
  for (int d=0;d<16;++d){
    float a=0.f;
#pragma unroll
    for (int c=0;c<32;++c) a += vs[c]*Wg[c*16+d];
    gv[d]=sigm(a);
  }
#pragma unroll
  for (int c=0;c<32;++c) vs[c] *= sigm(vs[c]);
#pragma unroll
  for (int d=0;d<16;++d){ vv[d*3]*=gv[d]; vv[d*3+1]*=gv[d]; vv[d*3+2]*=gv[d]; }

  // second CG (scalar weights): vs2, then flat_s = vs2 @ Wvl_s
  float vs2[48];
#pragma unroll
  for (int c=0;c<32;++c) vs2[c] = w2[c]*vs[c]*y0;
#pragma unroll
  for (int k=0;k<16;++k){
    float dt = (vv[k*3]*y1_0 + vv[k*3+1]*y1_1 + vv[k*3+2]*y1_2)*is3;
    vs2[32+k] = w2[80+k]*dt;
  }

  float* aggrow = agg + (size_t)dst*160;
#pragma unroll 1
  for (int o=0;o<40;++o){
    float a=0.f;
#pragma unroll
    for (int c=0;c<48;++c) a += vs2[c]*Wvls[c*64+o];
    atomicAdd(aggrow+o, a*a0);
  }
#pragma unroll 1
  for (int o=40;o<64;++o){
    float a=0.f;
#pragma unroll
    for (int c=0;c<48;++c) a += vs2[c]*Wvls[c*64+o];
    atomicAdd(aggrow+o, a*a1);
  }

  // flat_v = einsum(vv2, Wvl_v) decomposed (A2 computed per-d as scalar)
  float t2[32];
#pragma unroll
  for (int c=0;c<32;++c) t2[c] = w2[32+c]*vs[c];
  float p2[48], q2[48];
#pragma unroll
  for (int k=0;k<16;++k){
    float vx=vv[k*3], vy=vv[k*3+1], vz=vv[k*3+2];
    float u = w2[64+k]*y0;
    p2[k*3]=u*vx; p2[k*3+1]=u*vy; p2[k*3+2]=u*vz;
    float cx=(vy*y1_2 - vz*y1_1)*is2;
    float cy=(vz*y1_0 - vx*y1_2)*is2;
    float cz=(vx*y1_1 - vy*y1_0)*is2;
    q2[k*3]=w2[96+k]*cx; q2[k*3+1]=w2[96+k]*cy; q2[k*3+2]=w2[96+k]*cz;
  }
#pragma unroll 1
  for (int d=0; d<32; ++d){
    float A2=0.f;
#pragma unroll
    for (int c=0;c<32;++c) A2 += t2[c]*Wvlv[c*32+d];
    float b0=A2*y1_0, b1=A2*y1_1, b2=A2*y1_2;
#pragma unroll
    for (int k=0;k<16;++k){
      float wB = Wvlv[(32+k)*32+d];
      float wC = Wvlv[(48+k)*32+d];
      b0 += p2[k*3+0]*wB + q2[k*3+0]*wC;
      b1 += p2[k*3+1]*wB + q2[k*3+1]*wC;
      b2 += p2[k*3+2]*wB + q2[k*3+2]*wC;
    }
    int o = 64 + d*3;
    float w0 = (o   < 80) ? a1 : ((o   < 120) ? a2 : a3);
    float w1 = (o+1 < 80) ? a1 : ((o+1 < 120) ? a2 : a3);
    float ww = (o+2 < 80) ? a1 : ((o+2 < 120) ? a2 : a3);
    atomicAdd(aggrow+o,   b0*w0);
    atomicAdd(aggrow+o+1, b1*w1);
    atomicAdd(aggrow+o+2, b2*ww);
  }
}

// ------------- output pass: Wp projections + residual ----------------------
__global__ __launch_bounds__(256) void k_out(
    const float* __restrict__ node, const float* __restrict__ agg,
    const float* __restrict__ Wps, const float* __restrict__ Wpv,
    float* __restrict__ out)
{
  int n = blockIdx.x * 256 + threadIdx.x;
  if (n >= NN) return;
  const float* ar = agg + (size_t)n*160;
  const float* nr = node + (size_t)n*80;
  float* orow = out + (size_t)n*80;

  float a[64];
  { const float4* ap = reinterpret_cast<const float4*>(ar);
#pragma unroll
    for (int i=0;i<16;++i){ float4 t=ap[i];
      a[i*4]=t.x; a[i*4+1]=t.y; a[i*4+2]=t.z; a[i*4+3]=t.w; } }
#pragma unroll 1
  for (int d=0; d<32; ++d){
    float acc=0.f;
#pragma unroll
    for (int c=0;c<64;++c) acc += a[c]*Wps[c*32+d];
    orow[d] = nr[d] + acc;
  }
  float b[96];
  { const float4* bp = reinterpret_cast<const float4*>(ar + 64);
#pragma unroll
    for (int i=0;i<24;++i){ float4 t=bp[i];
      b[i*4]=t.x; b[i*4+1]=t.y; b[i*4+2]=t.z; b[i*4+3]=t.w; } }
#pragma unroll 1
  for (int d=0; d<16; ++d){
#pragma unroll
    for (int x=0;x<3;++x){
      float acc=0.f;
#pragma unroll
      for (int c=0;c<32;++c) acc += b[c*3+x]*Wpv[c*16+d];
      orow[32+d*3+x] = nr[32+d*3+x] + acc;
    }
  }
}

extern "C" void kernel_launch(void* const* d_in, const int* in_sizes, int n_in,
                              void* d_out, int out_size, void* d_ws, size_t ws_size,
                              hipStream_t stream)
{
  const float* node   = (const float*)d_in[0];
  const float* rbf    = (const float*)d_in[1];
  const float* rsh    = (const float*)d_in[2];
  const float* Wsrc_s = (const float*)d_in[3];
  const float* Wsrc_v = (const float*)d_in[4];
  const float* Wdst_s = (const float*)d_in[5];
  const float* Wdst_v = (const float*)d_in[6];
  const float* W_rbf  = (const float*)d_in[7];
  const float* dtp2   = (const float*)d_in[8];
  const float* Wa     = (const float*)d_in[9];
  const float* adot   = (const float*)d_in[10];
  const float* Wval_s = (const float*)d_in[11];
  const float* Wval_v = (const float*)d_in[12];
  const float* Wg     = (const float*)d_in[13];
  const float* Wvl_s  = (const float*)d_in[14];
  const float* Wvl_v  = (const float*)d_in[15];
  const float* Wp_s   = (const float*)d_in[16];
  const float* Wp_v   = (const float*)d_in[17];
  const int*   ei     = (const int*)d_in[18];

  float* ws = (float*)d_ws;
  size_t off = 0;
  float* ss  = ws + off; off += (size_t)NN*32;
  float* ds  = ws + off; off += (size_t)NN*32;
  float* sv  = ws + off; off += (size_t)NN*48;
  float* dv  = ws + off; off += (size_t)NN*48;
  float* lg  = ws + off; off += (size_t)EE*4;
  unsigned* menc = (unsigned*)(ws + off); off += (size_t)NN*4;
  float* den = ws + off; off += (size_t)NN*4;
  float* agg = ws + off; off += (size_t)NN*160;

  if (ws_size < off * sizeof(float)) return;  // workspace too small: fail loudly

  // zero m_enc (0 < every encoded finite float), denom, agg (contiguous)
  hipMemsetAsync(menc, 0, (size_t)NN*(4+4+160)*sizeof(float), stream);

  k_node <<<NN/256, 256, 0, stream>>>(node, Wsrc_s, Wsrc_v, Wdst_s, Wdst_v, ss, ds, sv, dv);
  k_edgeA<<<EE/256, 256, 0, stream>>>(ei, rbf, rsh, W_rbf, Wa, adot, ss, ds, sv, dv, lg, menc);
  k_edgeB<<<EE/256, 256, 0, stream>>>(ei, lg, menc, den);
  k_edgeC<<<EE/256, 256, 0, stream>>>(ei, rbf, rsh, W_rbf, Wval_s, Wval_v, Wg, Wvl_s, Wvl_v,
                                      dtp2, ss, ds, sv, dv, lg, menc, den, agg);
  k_out  <<<NN/256, 256, 0, stream>>>(node, agg, Wp_s, Wp_v, (float*)d_out);
}

// Round 2
// 1697.372 us; speedup vs baseline: 1.5340x; 1.5340x over previous
//
#include <hip/hip_runtime.h>

#define NN 32768
#define EE 262144

static __device__ __forceinline__ unsigned enc_f(float x){
  unsigned u = __float_as_uint(x);
  return (u & 0x80000000u) ? ~u : (u | 0x80000000u);
}
static __device__ __forceinline__ float dec_f(unsigned u){
  return __uint_as_float((u & 0x80000000u) ? (u ^ 0x80000000u) : ~u);
}
static __device__ __forceinline__ float sigm(float x){
  return 1.0f / (1.0f + __expf(-x));
}

// ---------------- node pass: o3-layernorm + src/dst linears ----------------
__global__ __launch_bounds__(256) void k_node(
    const float* __restrict__ node,
    const float* __restrict__ Wss, const float* __restrict__ Wsv,
    const float* __restrict__ Wds, const float* __restrict__ Wdv,
    float* __restrict__ ss, float* __restrict__ ds,
    float* __restrict__ sv, float* __restrict__ dv)
{
  int n = blockIdx.x * 256 + threadIdx.x;
  if (n >= NN) return;
  const float4* row = reinterpret_cast<const float4*>(node + (size_t)n * 80);
  float s[32], v[48];
#pragma unroll
  for (int i = 0; i < 8; ++i){
    float4 t = row[i];
    s[i*4+0]=t.x; s[i*4+1]=t.y; s[i*4+2]=t.z; s[i*4+3]=t.w;
  }
#pragma unroll
  for (int i = 0; i < 12; ++i){
    float4 t = row[8+i];
    v[i*4+0]=t.x; v[i*4+1]=t.y; v[i*4+2]=t.z; v[i*4+3]=t.w;
  }
  float mean = 0.f;
#pragma unroll
  for (int i=0;i<32;++i) mean += s[i];
  mean *= (1.0f/32.0f);
  float var = 0.f;
#pragma unroll
  for (int i=0;i<32;++i){ float d0 = s[i]-mean; var += d0*d0; }
  var *= (1.0f/32.0f);
  float sinv = rsqrtf(var + 1e-5f);
#pragma unroll
  for (int i=0;i<32;++i) s[i] = (s[i]-mean)*sinv;
  float n2 = 0.f;
#pragma unroll
  for (int i=0;i<48;++i) n2 += v[i]*v[i];
  n2 *= (1.0f/16.0f);
  float vinv = rsqrtf(n2 + 1e-5f);
#pragma unroll
  for (int i=0;i<48;++i) v[i] *= vinv;

  float* ssr = ss + (size_t)n*32;
  float* dsr = ds + (size_t)n*32;
#pragma unroll 1
  for (int d=0; d<32; ++d){
    float a=0.f, b=0.f;
#pragma unroll
    for (int c=0;c<32;++c){ a += s[c]*Wss[c*32+d]; b += s[c]*Wds[c*32+d]; }
    ssr[d]=a; dsr[d]=b;
  }
  float* svr = sv + (size_t)n*48;
  float* dvr = dv + (size_t)n*48;
#pragma unroll 1
  for (int d=0; d<16; ++d){
#pragma unroll
    for (int x=0;x<3;++x){
      float a=0.f, b=0.f;
#pragma unroll
      for (int c=0;c<16;++c){ a += v[c*3+x]*Wsv[c*16+d]; b += v[c*3+x]*Wdv[c*16+d]; }
      svr[d*3+x]=a; dvr[d*3+x]=b;
    }
  }
}

// ---------------- CSR build ----------------
__global__ __launch_bounds__(256) void k_hist(const int* __restrict__ ei, int* __restrict__ deg){
  int e = blockIdx.x*256 + threadIdx.x;
  if (e >= EE) return;
  atomicAdd(deg + ei[EE + e], 1);
}

__global__ __launch_bounds__(1024) void k_scan(const int* __restrict__ deg,
                                               int* __restrict__ base, int* __restrict__ cursor){
  __shared__ int lds[1024];
  int t = threadIdx.x;
  int v[32];
#pragma unroll
  for (int i=0;i<32;++i) v[i] = deg[t*32+i];
  int run = 0;
#pragma unroll
  for (int i=0;i<32;++i){ int x=v[i]; v[i]=run; run+=x; }
  lds[t]=run; __syncthreads();
  for (int off=1; off<1024; off<<=1){
    int add = (t>=off) ? lds[t-off] : 0;
    __syncthreads();
    lds[t] += add;
    __syncthreads();
  }
  int pre = (t==0) ? 0 : lds[t-1];
#pragma unroll
  for (int i=0;i<32;++i){ int b = pre + v[i]; base[t*32+i]=b; cursor[t*32+i]=b; }
}

__global__ __launch_bounds__(256) void k_scatter(const int* __restrict__ ei,
                                                 int* __restrict__ cursor, int* __restrict__ csr){
  int e = blockIdx.x*256 + threadIdx.x;
  if (e >= EE) return;
  int d = ei[EE + e];
  int pos = atomicAdd(cursor + d, 1);
  csr[pos] = e;
}

// ------------- edge pass A: attention logits ------------------------------
__global__ __launch_bounds__(256) void k_edgeA(
    const int* __restrict__ ei,
    const float* __restrict__ rbf, const float* __restrict__ rsh,
    const float* __restrict__ Wrbf, const float* __restrict__ Wa,
    const float* __restrict__ adot,
    const float* __restrict__ ss, const float* __restrict__ ds,
    const float* __restrict__ sv, const float* __restrict__ dv,
    float* __restrict__ logits)
{
  int e = blockIdx.x * 256 + threadIdx.x;
  if (e >= EE) return;
  int src = ei[e], dst = ei[EE + e];
  float r[16];
  { const float4* rp = reinterpret_cast<const float4*>(rbf + (size_t)e*16);
#pragma unroll
    for (int i=0;i<4;++i){ float4 t=rp[i]; r[i*4]=t.x; r[i*4+1]=t.y; r[i*4+2]=t.z; r[i*4+3]=t.w; } }
  float4 yv = reinterpret_cast<const float4*>(rsh)[e];
  const float y0=yv.x, y1x=yv.y, y1y=yv.z, y1z=yv.w;

  float ms[48];
  { const float4* ap = reinterpret_cast<const float4*>(ss + (size_t)src*32);
    const float4* bp = reinterpret_cast<const float4*>(ds + (size_t)dst*32);
    float s_[32];
#pragma unroll
    for (int i=0;i<8;++i){ float4 a=ap[i], b=bp[i];
      s_[i*4]=a.x+b.x; s_[i*4+1]=a.y+b.y; s_[i*4+2]=a.z+b.z; s_[i*4+3]=a.w+b.w; }
#pragma unroll
    for (int c=0;c<32;++c){
      float w=0.f;
#pragma unroll
      for (int j=0;j<16;++j) w += r[j]*Wrbf[j*112+c];
      ms[c] = w * s_[c] * y0;
    }
  }
  {
    const float4* ap = reinterpret_cast<const float4*>(sv + (size_t)src*48);
    const float4* bp = reinterpret_cast<const float4*>(dv + (size_t)dst*48);
    float v_[48];
#pragma unroll
    for (int i=0;i<12;++i){ float4 a=ap[i], b=bp[i];
      v_[i*4]=a.x+b.x; v_[i*4+1]=a.y+b.y; v_[i*4+2]=a.z+b.z; v_[i*4+3]=a.w+b.w; }
    const float is3 = 0.57735026918962576f;
#pragma unroll
    for (int k=0;k<16;++k){
      float w=0.f;
#pragma unroll
      for (int j=0;j<16;++j) w += r[j]*Wrbf[j*112+80+k];
      float dt = (v_[k*3]*y1x + v_[k*3+1]*y1y + v_[k*3+2]*y1z)*is3;
      ms[32+k] = w*dt;
    }
  }
#pragma unroll 1
  for (int h=0;h<4;++h){
    float acc=0.f;
#pragma unroll 1
    for (int j=0;j<16;++j){
      float t=0.f;
#pragma unroll
      for (int c=0;c<48;++c) t += ms[c]*Wa[c*64 + h*16 + j];
      t = (t > 0.f) ? t : 0.2f*t;
      acc += t * adot[h*16+j];
    }
    logits[(size_t)e*4+h] = acc;
  }
}

// ------------- per-(dst,head) softmax stats via CSR (no atomics) ----------
__global__ __launch_bounds__(256) void k_soft(
    const int* __restrict__ base, const int* __restrict__ deg,
    const int* __restrict__ csr, const float* __restrict__ logits,
    float* __restrict__ m, float* __restrict__ iden)
{
  int id = blockIdx.x*256 + threadIdx.x;
  if (id >= NN*4) return;
  int d = id >> 2, h = id & 3;
  int b = base[d], n = deg[d];
  float mm = -3.4e38f;
  for (int i=0;i<n;++i){ int e = csr[b+i]; mm = fmaxf(mm, logits[(size_t)e*4+h]); }
  float s = 0.f;
  for (int i=0;i<n;++i){ int e = csr[b+i]; s += __expf(logits[(size_t)e*4+h] - mm); }
  m[id] = mm;
  iden[id] = (n>0) ? 1.0f/s : 0.f;
}

// ------------- edge pass C: value pipeline, streamed per-edge output -------
__global__ __launch_bounds__(256) void k_edgeC2(
    const int* __restrict__ csr, const int* __restrict__ ei,
    const float* __restrict__ rbf, const float* __restrict__ rsh,
    const float* __restrict__ Wrbf,
    const float* __restrict__ Wvals, const float* __restrict__ Wvalv,
    const float* __restrict__ Wg, const float* __restrict__ Wvls,
    const float* __restrict__ Wvlv, const float* __restrict__ w2,
    const float* __restrict__ ss, const float* __restrict__ ds,
    const float* __restrict__ sv, const float* __restrict__ dv,
    const float* __restrict__ logits, const float* __restrict__ m,
    const float* __restrict__ iden, float* __restrict__ wflat)
{
  int pidx = blockIdx.x * 256 + threadIdx.x;
  if (pidx >= EE) return;
  int e = csr[pidx];
  int src = ei[e], dst = ei[EE + e];

  float4 yv = reinterpret_cast<const float4*>(rsh)[e];
  const float y0=yv.x, y1_0=yv.y, y1_1=yv.z, y1_2=yv.w;

  float a0,a1,a2,a3;
  {
    float4 l4 = reinterpret_cast<const float4*>(logits)[e];
    a0 = __expf(l4.x - m[(size_t)dst*4+0]) * iden[(size_t)dst*4+0];
    a1 = __expf(l4.y - m[(size_t)dst*4+1]) * iden[(size_t)dst*4+1];
    a2 = __expf(l4.z - m[(size_t)dst*4+2]) * iden[(size_t)dst*4+2];
    a3 = __expf(l4.w - m[(size_t)dst*4+3]) * iden[(size_t)dst*4+3];
  }

  float r[16];
  { const float4* rp = reinterpret_cast<const float4*>(rbf + (size_t)e*16);
#pragma unroll
    for (int i=0;i<4;++i){ float4 t=rp[i]; r[i*4]=t.x; r[i*4+1]=t.y; r[i*4+2]=t.z; r[i*4+3]=t.w; } }

  float s_[32];
  { const float4* ap = reinterpret_cast<const float4*>(ss + (size_t)src*32);
    const float4* bp = reinterpret_cast<const float4*>(ds + (size_t)dst*32);
#pragma unroll
    for (int i=0;i<8;++i){ float4 a=ap[i], b=bp[i];
      s_[i*4]=a.x+b.x; s_[i*4+1]=a.y+b.y; s_[i*4+2]=a.z+b.z; s_[i*4+3]=a.w+b.w; } }
  float v_[48];
  { const float4* ap = reinterpret_cast<const float4*>(sv + (size_t)src*48);
    const float4* bp = reinterpret_cast<const float4*>(dv + (size_t)dst*48);
#pragma unroll
    for (int i=0;i<12;++i){ float4 a=ap[i], b=bp[i];
      v_[i*4]=a.x+b.x; v_[i*4+1]=a.y+b.y; v_[i*4+2]=a.z+b.z; v_[i*4+3]=a.w+b.w; } }

  const float is3 = 0.57735026918962576f;
  const float is2 = 0.70710678118654752f;

  float ms[48];
#pragma unroll
  for (int c=0;c<32;++c){
    float w=0.f;
#pragma unroll
    for (int j=0;j<16;++j) w += r[j]*Wrbf[j*112+c];
    ms[c] = w * s_[c] * y0;
  }
#pragma unroll
  for (int k=0;k<16;++k){
    float w=0.f;
#pragma unroll
    for (int j=0;j<16;++j) w += r[j]*Wrbf[j*112+80+k];
    float dt = (v_[k*3]*y1_0 + v_[k*3+1]*y1_1 + v_[k*3+2]*y1_2)*is3;
    ms[32+k] = w*dt;
  }

  float t_[32];
#pragma unroll
  for (int c=0;c<32;++c){
    float w=0.f;
#pragma unroll
    for (int j=0;j<16;++j) w += r[j]*Wrbf[j*112+32+c];
    t_[c] = w * s_[c];
  }
  float sa[16];
#pragma unroll
  for (int d=0;d<16;++d){
    float a=0.f;
#pragma unroll
    for (int c=0;c<32;++c) a += t_[c]*Wvalv[c*16+d];
    sa[d]=a;
  }
  float p[48], q[48];
#pragma unroll
  for (int k=0;k<16;++k){
    float wvs=0.f, wvc=0.f;
#pragma unroll
    for (int j=0;j<16;++j){ wvs += r[j]*Wrbf[j*112+64+k]; wvc += r[j]*Wrbf[j*112+96+k]; }
    float vx=v_[k*3], vy=v_[k*3+1], vz=v_[k*3+2];
    float u = wvs * y0;
    p[k*3]=u*vx; p[k*3+1]=u*vy; p[k*3+2]=u*vz;
    float cx=(vy*y1_2 - vz*y1_1)*is2;
    float cy=(vz*y1_0 - vx*y1_2)*is2;
    float cz=(vx*y1_1 - vy*y1_0)*is2;
    q[k*3]=wvc*cx; q[k*3+1]=wvc*cy; q[k*3+2]=wvc*cz;
  }
  float vv[48];
#pragma unroll
  for (int d=0;d<16;++d){
    float b0=sa[d]*y1_0, b1=sa[d]*y1_1, b2=sa[d]*y1_2;
#pragma unroll
    for (int k=0;k<16;++k){
      float wB = Wvalv[(32+k)*16+d];
      float wC = Wvalv[(48+k)*16+d];
      b0 += p[k*3+0]*wB + q[k*3+0]*wC;
      b1 += p[k*3+1]*wB + q[k*3+1]*wC;
      b2 += p[k*3+2]*wB + q[k*3+2]*wC;
    }
    vv[d*3]=b0; vv[d*3+1]=b1; vv[d*3+2]=b2;
  }

  float vs[32];
#pragma unroll
  for (int d=0;d<32;++d){
    float a=0.f;
#pragma unroll
    for (int c=0;c<48;++c) a += ms[c]*Wvals[c*32+d];
    vs[d]=a;
  }
  float gv[16];
#pragma unroll
  for (int d=0;d<16;++d){
    float a=0.f;
#pragma unroll
    for (int c=0;c<32;++c) a += vs[c]*Wg[c*16+d];
    gv[d]=sigm(a);
  }
#pragma unroll
  for (int c=0;c<32;++c) vs[c] *= sigm(vs[c]);
#pragma unroll
  for (int d=0;d<16;++d){ vv[d*3]*=gv[d]; vv[d*3+1]*=gv[d]; vv[d*3+2]*=gv[d]; }

  float vs2[48];
#pragma unroll
  for (int c=0;c<32;++c) vs2[c] = w2[c]*vs[c]*y0;
#pragma unroll
  for (int k=0;k<16;++k){
    float dt = (vv[k*3]*y1_0 + vv[k*3+1]*y1_1 + vv[k*3+2]*y1_2)*is3;
    vs2[32+k] = w2[80+k]*dt;
  }

  float* wrow = wflat + (size_t)pidx*160;
#pragma unroll 1
  for (int o4=0; o4<16; ++o4){
    float4 o;
    float aw = (o4 < 10) ? a0 : a1;
    {
      float acc0=0.f, acc1=0.f, acc2=0.f, acc3=0.f;
#pragma unroll
      for (int c=0;c<48;++c){
        float vc = vs2[c];
        acc0 += vc*Wvls[c*64+o4*4+0];
        acc1 += vc*Wvls[c*64+o4*4+1];
        acc2 += vc*Wvls[c*64+o4*4+2];
        acc3 += vc*Wvls[c*64+o4*4+3];
      }
      o.x=acc0*aw; o.y=acc1*aw; o.z=acc2*aw; o.w=acc3*aw;
    }
    reinterpret_cast<float4*>(wrow)[o4] = o;
  }

  float t2[32];
#pragma unroll
  for (int c=0;c<32;++c) t2[c] = w2[32+c]*vs[c];
  float p2[48], q2[48];
#pragma unroll
  for (int k=0;k<16;++k){
    float vx=vv[k*3], vy=vv[k*3+1], vz=vv[k*3+2];
    float u = w2[64+k]*y0;
    p2[k*3]=u*vx; p2[k*3+1]=u*vy; p2[k*3+2]=u*vz;
    float cx=(vy*y1_2 - vz*y1_1)*is2;
    float cy=(vz*y1_0 - vx*y1_2)*is2;
    float cz=(vx*y1_1 - vy*y1_0)*is2;
    q2[k*3]=w2[96+k]*cx; q2[k*3+1]=w2[96+k]*cy; q2[k*3+2]=w2[96+k]*cz;
  }
#pragma unroll 1
  for (int d=0; d<32; ++d){
    float A2=0.f;
#pragma unroll
    for (int c=0;c<32;++c) A2 += t2[c]*Wvlv[c*32+d];
    float b0=A2*y1_0, b1=A2*y1_1, b2=A2*y1_2;
#pragma unroll
    for (int k=0;k<16;++k){
      float wB = Wvlv[(32+k)*32+d];
      float wC = Wvlv[(48+k)*32+d];
      b0 += p2[k*3+0]*wB + q2[k*3+0]*wC;
      b1 += p2[k*3+1]*wB + q2[k*3+1]*wC;
      b2 += p2[k*3+2]*wB + q2[k*3+2]*wC;
    }
    int o = 64 + d*3;
    float w0 = (o   < 80) ? a1 : ((o   < 120) ? a2 : a3);
    float w1 = (o+1 < 80) ? a1 : ((o+1 < 120) ? a2 : a3);
    float ww = (o+2 < 80) ? a1 : ((o+2 < 120) ? a2 : a3);
    wrow[o]   = b0*w0;
    wrow[o+1] = b1*w1;
    wrow[o+2] = b2*ww;
  }
}

// ------------- gather: per-dst sum of weighted per-edge rows ---------------
__global__ __launch_bounds__(256) void k_gather(
    const int* __restrict__ base, const int* __restrict__ deg,
    const float* __restrict__ wflat, float* __restrict__ agg)
{
  int id = blockIdx.x*256 + threadIdx.x;
  if (id >= NN*40) return;
  int d = id / 40, c = id % 40;
  int b = base[d], n = deg[d];
  float4 acc = make_float4(0.f,0.f,0.f,0.f);
  for (int i=0;i<n;++i){
    float4 w = reinterpret_cast<const float4*>(wflat + (size_t)(b+i)*160)[c];
    acc.x += w.x; acc.y += w.y; acc.z += w.z; acc.w += w.w;
  }
  reinterpret_cast<float4*>(agg + (size_t)d*160)[c] = acc;
}

// ------------- output pass: Wp projections + residual ----------------------
__global__ __launch_bounds__(256) void k_out(
    const float* __restrict__ node, const float* __restrict__ agg,
    const float* __restrict__ Wps, const float* __restrict__ Wpv,
    float* __restrict__ out)
{
  int n = blockIdx.x * 256 + threadIdx.x;
  if (n >= NN) return;
  const float* ar = agg + (size_t)n*160;
  const float* nr = node + (size_t)n*80;
  float* orow = out + (size_t)n*80;

  float a[64];
  { const float4* ap = reinterpret_cast<const float4*>(ar);
#pragma unroll
    for (int i=0;i<16;++i){ float4 t=ap[i];
      a[i*4]=t.x; a[i*4+1]=t.y; a[i*4+2]=t.z; a[i*4+3]=t.w; } }
#pragma unroll 1
  for (int d=0; d<32; ++d){
    float acc=0.f;
#pragma unroll
    for (int c=0;c<64;++c) acc += a[c]*Wps[c*32+d];
    orow[d] = nr[d] + acc;
  }
  float b[96];
  { const float4* bp = reinterpret_cast<const float4*>(ar + 64);
#pragma unroll
    for (int i=0;i<24;++i){ float4 t=bp[i];
      b[i*4]=t.x; b[i*4+1]=t.y; b[i*4+2]=t.z; b[i*4+3]=t.w; } }
#pragma unroll 1
  for (int d=0; d<16; ++d){
#pragma unroll
    for (int x=0;x<3;++x){
      float acc=0.f;
#pragma unroll
      for (int c=0;c<32;++c) acc += b[c*3+x]*Wpv[c*16+d];
      orow[32+d*3+x] = nr[32+d*3+x] + acc;
    }
  }
}

// ================= FALLBACK (atomic path, if ws too small) =================
__global__ __launch_bounds__(256) void k_maxred(
    const int* __restrict__ ei, const float* __restrict__ logits,
    unsigned* __restrict__ menc)
{
  int e = blockIdx.x*256 + threadIdx.x;
  if (e >= EE) return;
  int dst = ei[EE + e];
  float4 l4 = reinterpret_cast<const float4*>(logits)[e];
  atomicMax(menc + ((size_t)dst*4+0), enc_f(l4.x));
  atomicMax(menc + ((size_t)dst*4+1), enc_f(l4.y));
  atomicMax(menc + ((size_t)dst*4+2), enc_f(l4.z));
  atomicMax(menc + ((size_t)dst*4+3), enc_f(l4.w));
}

__global__ __launch_bounds__(256) void k_edgeB(
    const int* __restrict__ ei, const float* __restrict__ logits,
    const unsigned* __restrict__ menc, float* __restrict__ den)
{
  int e = blockIdx.x * 256 + threadIdx.x;
  if (e >= EE) return;
  int dst = ei[EE + e];
  float4 l4 = reinterpret_cast<const float4*>(logits)[e];
  atomicAdd(den + ((size_t)dst*4+0), __expf(l4.x - dec_f(menc[(size_t)dst*4+0])));
  atomicAdd(den + ((size_t)dst*4+1), __expf(l4.y - dec_f(menc[(size_t)dst*4+1])));
  atomicAdd(den + ((size_t)dst*4+2), __expf(l4.z - dec_f(menc[(size_t)dst*4+2])));
  atomicAdd(den + ((size_t)dst*4+3), __expf(l4.w - dec_f(menc[(size_t)dst*4+3])));
}

__global__ __launch_bounds__(256) void k_edgeC_at(
    const int* __restrict__ ei,
    const float* __restrict__ rbf, const float* __restrict__ rsh,
    const float* __restrict__ Wrbf,
    const float* __restrict__ Wvals, const float* __restrict__ Wvalv,
    const float* __restrict__ Wg, const float* __restrict__ Wvls,
    const float* __restrict__ Wvlv, const float* __restrict__ w2,
    const float* __restrict__ ss, const float* __restrict__ ds,
    const float* __restrict__ sv, const float* __restrict__ dv,
    const float* __restrict__ logits, const unsigned* __restrict__ menc,
    const float* __restrict__ den, float* __restrict__ agg)
{
  int e = blockIdx.x * 256 + threadIdx.x;
  if (e >= EE) return;
  int src = ei[e], dst = ei[EE + e];

  float4 yv = reinterpret_cast<const float4*>(rsh)[e];
  const float y0=yv.x, y1_0=yv.y, y1_1=yv.z, y1_2=yv.w;

  float a0,a1,a2,a3;
  {
    float4 l4 = reinterpret_cast<const float4*>(logits)[e];
    a0 = __expf(l4.x - dec_f(menc[(size_t)dst*4+0])) / den[(size_t)dst*4+0];
    a1 = __expf(l4.y - dec_f(menc[(size_t)dst*4+1])) / den[(size_t)dst*4+1];
    a2 = __expf(l4.z - dec_f(menc[(size_t)dst*4+2])) / den[(size_t)dst*4+2];
    a3 = __expf(l4.w - dec_f(menc[(size_t)dst*4+3])) / den[(size_t)dst*4+3];
  }

  float r[16];
  { const float4* rp = reinterpret_cast<const float4*>(rbf + (size_t)e*16);
#pragma unroll
    for (int i=0;i<4;++i){ float4 t=rp[i]; r[i*4]=t.x; r[i*4+1]=t.y; r[i*4+2]=t.z; r[i*4+3]=t.w; } }

  float s_[32];
  { const float4* ap = reinterpret_cast<const float4*>(ss + (size_t)src*32);
    const float4* bp = reinterpret_cast<const float4*>(ds + (size_t)dst*32);
#pragma unroll
    for (int i=0;i<8;++i){ float4 a=ap[i], b=bp[i];
      s_[i*4]=a.x+b.x; s_[i*4+1]=a.y+b.y; s_[i*4+2]=a.z+b.z; s_[i*4+3]=a.w+b.w; } }
  float v_[48];
  { const float4* ap = reinterpret_cast<const float4*>(sv + (size_t)src*48);
    const float4* bp = reinterpret_cast<const float4*>(dv + (size_t)dst*48);
#pragma unroll
    for (int i=0;i<12;++i){ float4 a=ap[i], b=bp[i];
      v_[i*4]=a.x+b.x; v_[i*4+1]=a.y+b.y; v_[i*4+2]=a.z+b.z; v_[i*4+3]=a.w+b.w; } }

  const float is3 = 0.57735026918962576f;
  const float is2 = 0.70710678118654752f;

  float ms[48];
#pragma unroll
  for (int c=0;c<32;++c){
    float w=0.f;
#pragma unroll
    for (int j=0;j<16;++j) w += r[j]*Wrbf[j*112+c];
    ms[c] = w * s_[c] * y0;
  }
#pragma unroll
  for (int k=0;k<16;++k){
    float w=0.f;
#pragma unroll
    for (int j=0;j<16;++j) w += r[j]*Wrbf[j*112+80+k];
    float dt = (v_[k*3]*y1_0 + v_[k*3+1]*y1_1 + v_[k*3+2]*y1_2)*is3;
    ms[32+k] = w*dt;
  }

  float t_[32];
#pragma unroll
  for (int c=0;c<32;++c){
    float w=0.f;
#pragma unroll
    for (int j=0;j<16;++j) w += r[j]*Wrbf[j*112+32+c];
    t_[c] = w * s_[c];
  }
  float sa[16];
#pragma unroll
  for (int d=0;d<16;++d){
    float a=0.f;
#pragma unroll
    for (int c=0;c<32;++c) a += t_[c]*Wvalv[c*16+d];
    sa[d]=a;
  }
  float p[48], q[48];
#pragma unroll
  for (int k=0;k<16;++k){
    float wvs=0.f, wvc=0.f;
#pragma unroll
    for (int j=0;j<16;++j){ wvs += r[j]*Wrbf[j*112+64+k]; wvc += r[j]*Wrbf[j*112+96+k]; }
    float vx=v_[k*3], vy=v_[k*3+1], vz=v_[k*3+2];
    float u = wvs * y0;
    p[k*3]=u*vx; p[k*3+1]=u*vy; p[k*3+2]=u*vz;
    float cx=(vy*y1_2 - vz*y1_1)*is2;
    float cy=(vz*y1_0 - vx*y1_2)*is2;
    float cz=(vx*y1_1 - vy*y1_0)*is2;
    q[k*3]=wvc*cx; q[k*3+1]=wvc*cy; q[k*3+2]=wvc*cz;
  }
  float vv[48];
#pragma unroll
  for (int d=0;d<16;++d){
    float b0=sa[d]*y1_0, b1=sa[d]*y1_1, b2=sa[d]*y1_2;
#pragma unroll
    for (int k=0;k<16;++k){
      float wB = Wvalv[(32+k)*16+d];
      float wC = Wvalv[(48+k)*16+d];
      b0 += p[k*3+0]*wB + q[k*3+0]*wC;
      b1 += p[k*3+1]*wB + q[k*3+1]*wC;
      b2 += p[k*3+2]*wB + q[k*3+2]*wC;
    }
    vv[d*3]=b0; vv[d*3+1]=b1; vv[d*3+2]=b2;
  }

  float vs[32];
#pragma unroll
  for (int d=0;d<32;++d){
    float a=0.f;
#pragma unroll
    for (int c=0;c<48;++c) a += ms[c]*Wvals[c*32+d];
    vs[d]=a;
  }
  float gv[16];
#pragma unroll
  for (int d=0;d<16;++d){
    float a=0.f;
#pragma unroll
    for (int c=0;c<32;++c) a += vs[c]*Wg[c*16+d];
    gv[d]=sigm(a);
  }
#pragma unroll
  for (int c=0;c<32;++c) vs[c] *= sigm(vs[c]);
#pragma unroll
  for (int d=0;d<16;++d){ vv[d*3]*=gv[d]; vv[d*3+1]*=gv[d]; vv[d*3+2]*=gv[d]; }

  float vs2[48];
#pragma unroll
  for (int c=0;c<32;++c) vs2[c] = w2[c]*vs[c]*y0;
#pragma unroll
  for (int k=0;k<16;++k){
    float dt = (vv[k*3]*y1_0 + vv[k*3+1]*y1_1 + vv[k*3+2]*y1_2)*is3;
    vs2[32+k] = w2[80+k]*dt;
  }

  float* aggrow = agg + (size_t)dst*160;
#pragma unroll 1
  for (int o=0;o<40;++o){
    float a=0.f;
#pragma unroll
    for (int c=0;c<48;++c) a += vs2[c]*Wvls[c*64+o];
    atomicAdd(aggrow+o, a*a0);
  }
#pragma unroll 1
  for (int o=40;o<64;++o){
    float a=0.f;
#pragma unroll
    for (int c=0;c<48;++c) a += vs2[c]*Wvls[c*64+o];
    atomicAdd(aggrow+o, a*a1);
  }

  float t2[32];
#pragma unroll
  for (int c=0;c<32;++c) t2[c] = w2[32+c]*vs[c];
  float p2[48], q2[48];
#pragma unroll
  for (int k=0;k<16;++k){
    float vx=vv[k*3], vy=vv[k*3+1], vz=vv[k*3+2];
    float u = w2[64+k]*y0;
    p2[k*3]=u*vx; p2[k*3+1]=u*vy; p2[k*3+2]=u*vz;
    float cx=(vy*y1_2 - vz*y1_1)*is2;
    float cy=(vz*y1_0 - vx*y1_2)*is2;
    float cz=(vx*y1_1 - vy*y1_0)*is2;
    q2[k*3]=w2[96+k]*cx; q2[k*3+1]=w2[96+k]*cy; q2[k*3+2]=w2[96+k]*cz;
  }
#pragma unroll 1
  for (int d=0; d<32; ++d){
    float A2=0.f;
#pragma unroll
    for (int c=0;c<32;++c) A2 += t2[c]*Wvlv[c*32+d];
    float b0=A2*y1_0, b1=A2*y1_1, b2=A2*y1_2;
#pragma unroll
    for (int k=0;k<16;++k){
      float wB = Wvlv[(32+k)*32+d];
      float wC = Wvlv[(48+k)*32+d];
      b0 += p2[k*3+0]*wB + q2[k*3+0]*wC;
      b1 += p2[k*3+1]*wB + q2[k*3+1]*wC;
      b2 += p2[k*3+2]*wB + q2[k*3+2]*wC;
    }
    int o = 64 + d*3;
    float w0 = (o   < 80) ? a1 : ((o   < 120) ? a2 : a3);
    float w1 = (o+1 < 80) ? a1 : ((o+1 < 120) ? a2 : a3);
    float ww = (o+2 < 80) ? a1 : ((o+2 < 120) ? a2 : a3);
    atomicAdd(aggrow+o,   b0*w0);
    atomicAdd(aggrow+o+1, b1*w1);
    atomicAdd(aggrow+o+2, b2*ww);
  }
}

extern "C" void kernel_launch(void* const* d_in, const int* in_sizes, int n_in,
                              void* d_out, int out_size, void* d_ws, size_t ws_size,
                              hipStream_t stream)
{
  const float* node   = (const float*)d_in[0];
  const float* rbf    = (const float*)d_in[1];
  const float* rsh    = (const float*)d_in[2];
  const float* Wsrc_s = (const float*)d_in[3];
  const float* Wsrc_v = (const float*)d_in[4];
  const float* Wdst_s = (const float*)d_in[5];
  const float* Wdst_v = (const float*)d_in[6];
  const float* W_rbf  = (const float*)d_in[7];
  const float* dtp2   = (const float*)d_in[8];
  const float* Wa     = (const float*)d_in[9];
  const float* adot   = (const float*)d_in[10];
  const float* Wval_s = (const float*)d_in[11];
  const float* Wval_v = (const float*)d_in[12];
  const float* Wg     = (const float*)d_in[13];
  const float* Wvl_s  = (const float*)d_in[14];
  const float* Wvl_v  = (const float*)d_in[15];
  const float* Wp_s   = (const float*)d_in[16];
  const float* Wp_v   = (const float*)d_in[17];
  const int*   ei     = (const int*)d_in[18];

  float* ws = (float*)d_ws;

  // ---- new-path layout ----
  size_t off = 0;
  float* ss   = ws + off; off += (size_t)NN*32;
  float* ds   = ws + off; off += (size_t)NN*32;
  float* sv   = ws + off; off += (size_t)NN*48;
  float* dv   = ws + off; off += (size_t)NN*48;
  float* lg   = ws + off; off += (size_t)EE*4;
  float* m    = ws + off; off += (size_t)NN*4;
  float* iden = ws + off; off += (size_t)NN*4;
  int* deg    = (int*)(ws + off); off += (size_t)NN;
  int* base   = (int*)(ws + off); off += (size_t)NN;
  int* cursor = (int*)(ws + off); off += (size_t)NN;
  int* csr    = (int*)(ws + off); off += (size_t)EE;
  float* agg  = ws + off; off += (size_t)NN*160;
  float* wflat= ws + off; off += (size_t)EE*160;
  size_t need_new = off * sizeof(float);

  if (ws_size >= need_new){
    hipMemsetAsync(deg, 0, (size_t)NN*sizeof(int), stream);
    k_node   <<<NN/256, 256, 0, stream>>>(node, Wsrc_s, Wsrc_v, Wdst_s, Wdst_v, ss, ds, sv, dv);
    k_hist   <<<EE/256, 256, 0, stream>>>(ei, deg);
    k_scan   <<<1, 1024, 0, stream>>>(deg, base, cursor);
    k_scatter<<<EE/256, 256, 0, stream>>>(ei, cursor, csr);
    k_edgeA  <<<EE/256, 256, 0, stream>>>(ei, rbf, rsh, W_rbf, Wa, adot, ss, ds, sv, dv, lg);
    k_soft   <<<(NN*4)/256, 256, 0, stream>>>(base, deg, csr, lg, m, iden);
    k_edgeC2 <<<EE/256, 256, 0, stream>>>(csr, ei, rbf, rsh, W_rbf, Wval_s, Wval_v, Wg, Wvl_s,
                                          Wvl_v, dtp2, ss, ds, sv, dv, lg, m, iden, wflat);
    k_gather <<<(NN*40)/256, 256, 0, stream>>>(base, deg, wflat, agg);
    k_out    <<<NN/256, 256, 0, stream>>>(node, agg, Wp_s, Wp_v, (float*)d_out);
    return;
  }

  // ---- fallback atomic path ----
  off = 0;
  ss   = ws + off; off += (size_t)NN*32;
  ds   = ws + off; off += (size_t)NN*32;
  sv   = ws + off; off += (size_t)NN*48;
  dv   = ws + off; off += (size_t)NN*48;
  lg   = ws + off; off += (size_t)EE*4;
  unsigned* menc = (unsigned*)(ws + off); off += (size_t)NN*4;
  float* den = ws + off; off += (size_t)NN*4;
  agg  = ws + off; off += (size_t)NN*160;
  if (ws_size < off * sizeof(float)) return;

  hipMemsetAsync(menc, 0, (size_t)NN*(4+4+160)*sizeof(float), stream);
  k_node   <<<NN/256, 256, 0, stream>>>(node, Wsrc_s, Wsrc_v, Wdst_s, Wdst_v, ss, ds, sv, dv);
  k_edgeA  <<<EE/256, 256, 0, stream>>>(ei, rbf, rsh, W_rbf, Wa, adot, ss, ds, sv, dv, lg);
  k_maxred <<<EE/256, 256, 0, stream>>>(ei, lg, menc);
  k_edgeB  <<<EE/256, 256, 0, stream>>>(ei, lg, menc, den);
  k_edgeC_at<<<EE/256, 256, 0, stream>>>(ei, rbf, rsh, W_rbf, Wval_s, Wval_v, Wg, Wvl_s, Wvl_v,
                                         dtp2, ss, ds, sv, dv, lg, menc, den, agg);
  k_out    <<<NN/256, 256, 0, stream>>>(node, agg, Wp_s, Wp_v, (float*)d_out);
}

// Round 3
// 792.199 us; speedup vs baseline: 3.2867x; 2.1426x over previous
//
#include <hip/hip_runtime.h>

#define NN 32768
#define EE 262144

static __device__ __forceinline__ unsigned enc_f(float x){
  unsigned u = __float_as_uint(x);
  return (u & 0x80000000u) ? ~u : (u | 0x80000000u);
}
static __device__ __forceinline__ float dec_f(unsigned u){
  return __uint_as_float((u & 0x80000000u) ? (u ^ 0x80000000u) : ~u);
}
static __device__ __forceinline__ float sigm(float x){
  return 1.0f / (1.0f + __expf(-x));
}

// ---------------- node pass: o3-layernorm + src/dst linears ----------------
__global__ __launch_bounds__(256) void k_node(
    const float* __restrict__ node,
    const float* __restrict__ Wss, const float* __restrict__ Wsv,
    const float* __restrict__ Wds, const float* __restrict__ Wdv,
    float* __restrict__ ss, float* __restrict__ ds,
    float* __restrict__ sv, float* __restrict__ dv)
{
  int n = blockIdx.x * 256 + threadIdx.x;
  if (n >= NN) return;
  const float4* row = reinterpret_cast<const float4*>(node + (size_t)n * 80);
  float s[32], v[48];
#pragma unroll
  for (int i = 0; i < 8; ++i){
    float4 t = row[i];
    s[i*4+0]=t.x; s[i*4+1]=t.y; s[i*4+2]=t.z; s[i*4+3]=t.w;
  }
#pragma unroll
  for (int i = 0; i < 12; ++i){
    float4 t = row[8+i];
    v[i*4+0]=t.x; v[i*4+1]=t.y; v[i*4+2]=t.z; v[i*4+3]=t.w;
  }
  float mean = 0.f;
#pragma unroll
  for (int i=0;i<32;++i) mean += s[i];
  mean *= (1.0f/32.0f);
  float var = 0.f;
#pragma unroll
  for (int i=0;i<32;++i){ float d0 = s[i]-mean; var += d0*d0; }
  var *= (1.0f/32.0f);
  float sinv = rsqrtf(var + 1e-5f);
#pragma unroll
  for (int i=0;i<32;++i) s[i] = (s[i]-mean)*sinv;
  float n2 = 0.f;
#pragma unroll
  for (int i=0;i<48;++i) n2 += v[i]*v[i];
  n2 *= (1.0f/16.0f);
  float vinv = rsqrtf(n2 + 1e-5f);
#pragma unroll
  for (int i=0;i<48;++i) v[i] *= vinv;

  float* ssr = ss + (size_t)n*32;
  float* dsr = ds + (size_t)n*32;
#pragma unroll 1
  for (int d=0; d<32; ++d){
    float a=0.f, b=0.f;
#pragma unroll
    for (int c=0;c<32;++c){ a += s[c]*Wss[c*32+d]; b += s[c]*Wds[c*32+d]; }
    ssr[d]=a; dsr[d]=b;
  }
  float* svr = sv + (size_t)n*48;
  float* dvr = dv + (size_t)n*48;
#pragma unroll 1
  for (int d=0; d<16; ++d){
#pragma unroll
    for (int x=0;x<3;++x){
      float a=0.f, b=0.f;
#pragma unroll
      for (int c=0;c<16;++c){ a += v[c*3+x]*Wsv[c*16+d]; b += v[c*3+x]*Wdv[c*16+d]; }
      svr[d*3+x]=a; dvr[d*3+x]=b;
    }
  }
}

// ---------------- CSR build ----------------
__global__ __launch_bounds__(256) void k_hist(const int* __restrict__ ei, int* __restrict__ deg){
  int e = blockIdx.x*256 + threadIdx.x;
  if (e >= EE) return;
  atomicAdd(deg + ei[EE + e], 1);
}

__global__ __launch_bounds__(1024) void k_scan(const int* __restrict__ deg,
                                               int* __restrict__ base, int* __restrict__ cursor){
  __shared__ int lds[1024];
  int t = threadIdx.x;
  int v[32];
#pragma unroll
  for (int i=0;i<32;++i) v[i] = deg[t*32+i];
  int run = 0;
#pragma unroll
  for (int i=0;i<32;++i){ int x=v[i]; v[i]=run; run+=x; }
  lds[t]=run; __syncthreads();
  for (int off=1; off<1024; off<<=1){
    int add = (t>=off) ? lds[t-off] : 0;
    __syncthreads();
    lds[t] += add;
    __syncthreads();
  }
  int pre = (t==0) ? 0 : lds[t-1];
#pragma unroll
  for (int i=0;i<32;++i){ int b = pre + v[i]; base[t*32+i]=b; cursor[t*32+i]=b; }
}

__global__ __launch_bounds__(256) void k_scatter(const int* __restrict__ ei,
                                                 int* __restrict__ cursor, int* __restrict__ csr){
  int e = blockIdx.x*256 + threadIdx.x;
  if (e >= EE) return;
  int d = ei[EE + e];
  int pos = atomicAdd(cursor + d, 1);
  csr[pos] = e;
}

// ------------- edge pass A: attention logits ------------------------------
__global__ __launch_bounds__(256) void k_edgeA(
    const int* __restrict__ ei,
    const float* __restrict__ rbf, const float* __restrict__ rsh,
    const float* __restrict__ Wrbf, const float* __restrict__ Wa,
    const float* __restrict__ adot,
    const float* __restrict__ ss, const float* __restrict__ ds,
    const float* __restrict__ sv, const float* __restrict__ dv,
    float* __restrict__ logits)
{
  int e = blockIdx.x * 256 + threadIdx.x;
  if (e >= EE) return;
  int src = ei[e], dst = ei[EE + e];
  float r[16];
  { const float4* rp = reinterpret_cast<const float4*>(rbf + (size_t)e*16);
#pragma unroll
    for (int i=0;i<4;++i){ float4 t=rp[i]; r[i*4]=t.x; r[i*4+1]=t.y; r[i*4+2]=t.z; r[i*4+3]=t.w; } }
  float4 yv = reinterpret_cast<const float4*>(rsh)[e];
  const float y0=yv.x, y1x=yv.y, y1y=yv.z, y1z=yv.w;

  float ms[48];
  { const float4* ap = reinterpret_cast<const float4*>(ss + (size_t)src*32);
    const float4* bp = reinterpret_cast<const float4*>(ds + (size_t)dst*32);
    float s_[32];
#pragma unroll
    for (int i=0;i<8;++i){ float4 a=ap[i], b=bp[i];
      s_[i*4]=a.x+b.x; s_[i*4+1]=a.y+b.y; s_[i*4+2]=a.z+b.z; s_[i*4+3]=a.w+b.w; }
#pragma unroll
    for (int c=0;c<32;++c){
      float w=0.f;
#pragma unroll
      for (int j=0;j<16;++j) w += r[j]*Wrbf[j*112+c];
      ms[c] = w * s_[c] * y0;
    }
  }
  {
    const float4* ap = reinterpret_cast<const float4*>(sv + (size_t)src*48);
    const float4* bp = reinterpret_cast<const float4*>(dv + (size_t)dst*48);
    float v_[48];
#pragma unroll
    for (int i=0;i<12;++i){ float4 a=ap[i], b=bp[i];
      v_[i*4]=a.x+b.x; v_[i*4+1]=a.y+b.y; v_[i*4+2]=a.z+b.z; v_[i*4+3]=a.w+b.w; }
    const float is3 = 0.57735026918962576f;
#pragma unroll
    for (int k=0;k<16;++k){
      float w=0.f;
#pragma unroll
      for (int j=0;j<16;++j) w += r[j]*Wrbf[j*112+80+k];
      float dt = (v_[k*3]*y1x + v_[k*3+1]*y1y + v_[k*3+2]*y1z)*is3;
      ms[32+k] = w*dt;
    }
  }
#pragma unroll 1
  for (int h=0;h<4;++h){
    float acc=0.f;
#pragma unroll 1
    for (int j=0;j<16;++j){
      float t=0.f;
#pragma unroll
      for (int c=0;c<48;++c) t += ms[c]*Wa[c*64 + h*16 + j];
      t = (t > 0.f) ? t : 0.2f*t;
      acc += t * adot[h*16+j];
    }
    logits[(size_t)e*4+h] = acc;
  }
}

// ------------- per-(dst,head) softmax stats via CSR (no atomics) ----------
__global__ __launch_bounds__(256) void k_soft(
    const int* __restrict__ base, const int* __restrict__ deg,
    const int* __restrict__ csr, const float* __restrict__ logits,
    float* __restrict__ m, float* __restrict__ iden)
{
  int id = blockIdx.x*256 + threadIdx.x;
  if (id >= NN*4) return;
  int d = id >> 2, h = id & 3;
  int b = base[d], n = deg[d];
  float mm = -3.4e38f;
  for (int i=0;i<n;++i){ int e = csr[b+i]; mm = fmaxf(mm, logits[(size_t)e*4+h]); }
  float s = 0.f;
  for (int i=0;i<n;++i){ int e = csr[b+i]; s += __expf(logits[(size_t)e*4+h] - mm); }
  m[id] = mm;
  iden[id] = (n>0) ? 1.0f/s : 0.f;
}

// ===================== cooperative edge value pass =========================
// 32 lanes per edge; weights transposed in LDS; per-edge scratch in LDS.
// LDS weight offsets (floats):
#define OFF_RBF   0      // [112][16]
#define OFF_VALS  1792   // [32][48]
#define OFF_VVA   3328   // [16][32]
#define OFF_VVB   3840   // [16][16]
#define OFF_VVC   4096   // [16][16]
#define OFF_G     4352   // [16][32]
#define OFF_VLS   4864   // [64][48]
#define OFF_VLVA  7936   // [32][32]
#define OFF_VLVB  8960   // [32][16]
#define OFF_VLVC  9472   // [32][16]
#define OFF_W2    9984   // [112]
#define EDGOFF    10096
#define ESTRIDE   400
// per-edge scratch layout (floats, relative):
//   0: s_[32]   32: v_[48] ([k*3+x])   80: r[16]   96: y[4]   100: a[4]
// 104: ms[48] / vs2[48]   152: t_[32] / t2[32]   184: sa[16]
// 200: p[3][16] / p2[3][16]   248: q[3][16] / q2[3][16]
// 296: vs[32]   328: gv[16]   344: vv[48]

__global__ __launch_bounds__(256) void k_edgeC3(
    const int* __restrict__ csr, const int* __restrict__ ei,
    const float* __restrict__ rbf, const float* __restrict__ rsh,
    const float* __restrict__ Wrbf,
    const float* __restrict__ Wvals, const float* __restrict__ Wvalv,
    const float* __restrict__ Wg, const float* __restrict__ Wvls,
    const float* __restrict__ Wvlv, const float* __restrict__ w2,
    const float* __restrict__ ss, const float* __restrict__ ds,
    const float* __restrict__ sv, const float* __restrict__ dv,
    const float* __restrict__ logits, const float* __restrict__ m,
    const float* __restrict__ iden, float* __restrict__ wflat)
{
  __shared__ __align__(16) float SH[EDGOFF + 8*ESTRIDE];
  const int t = threadIdx.x;
  // ---- stage transposed weights ----
  for (int i=t; i<112*16; i+=256){ int d=i>>4, k=i&15; SH[OFF_RBF+i]  = Wrbf[k*112+d]; }
  for (int i=t; i<32*48;  i+=256){ int d=i/48, k=i-48*d; SH[OFF_VALS+i] = Wvals[k*32+d]; }
  for (int i=t; i<16*32;  i+=256){ int d=i>>5, k=i&31; SH[OFF_VVA+i]  = Wvalv[k*16+d]; }
  for (int i=t; i<16*16;  i+=256){ int d=i>>4, k=i&15; SH[OFF_VVB+i]  = Wvalv[(32+k)*16+d]; }
  for (int i=t; i<16*16;  i+=256){ int d=i>>4, k=i&15; SH[OFF_VVC+i]  = Wvalv[(48+k)*16+d]; }
  for (int i=t; i<16*32;  i+=256){ int d=i>>5, k=i&31; SH[OFF_G+i]    = Wg[k*16+d]; }
  for (int i=t; i<64*48;  i+=256){ int d=i/48, k=i-48*d; SH[OFF_VLS+i] = Wvls[k*64+d]; }
  for (int i=t; i<32*32;  i+=256){ int d=i>>5, k=i&31; SH[OFF_VLVA+i] = Wvlv[k*32+d]; }
  for (int i=t; i<32*16;  i+=256){ int d=i>>4, k=i&15; SH[OFF_VLVB+i] = Wvlv[(32+k)*32+d]; }
  for (int i=t; i<32*16;  i+=256){ int d=i>>4, k=i&15; SH[OFF_VLVC+i] = Wvlv[(48+k)*32+d]; }
  for (int i=t; i<112;    i+=256){ SH[OFF_W2+i] = w2[i]; }
  __syncthreads();

  const int g = t >> 5;
  const int c = t & 31;
  float* E = &SH[EDGOFF + g*ESTRIDE];
  const float IS3 = 0.57735026918962576f;
  const float IS2 = 0.70710678118654752f;

#pragma unroll 1
  for (int tile=0; tile<16; ++tile){
    const int pidx = blockIdx.x*128 + tile*8 + g;
    const int e = csr[pidx];
    const int src = ei[e], dst = ei[EE + e];

    // ---- phase 0: load edge data into LDS ----
    if (c < 8){
      float4 a = *reinterpret_cast<const float4*>(ss + (size_t)src*32 + c*4);
      float4 b = *reinterpret_cast<const float4*>(ds + (size_t)dst*32 + c*4);
      float4 o; o.x=a.x+b.x; o.y=a.y+b.y; o.z=a.z+b.z; o.w=a.w+b.w;
      *reinterpret_cast<float4*>(&E[c*4]) = o;
    } else if (c < 20){
      int i = c-8;
      float4 a = *reinterpret_cast<const float4*>(sv + (size_t)src*48 + i*4);
      float4 b = *reinterpret_cast<const float4*>(dv + (size_t)dst*48 + i*4);
      float4 o; o.x=a.x+b.x; o.y=a.y+b.y; o.z=a.z+b.z; o.w=a.w+b.w;
      *reinterpret_cast<float4*>(&E[32+i*4]) = o;
    } else if (c < 24){
      int i = c-20;
      *reinterpret_cast<float4*>(&E[80+i*4]) =
          *reinterpret_cast<const float4*>(rbf + (size_t)e*16 + i*4);
    } else if (c == 24){
      *reinterpret_cast<float4*>(&E[96]) =
          *reinterpret_cast<const float4*>(rsh + (size_t)e*4);
    } else if (c == 25){
      float4 l4 = *reinterpret_cast<const float4*>(logits + (size_t)e*4);
      float4 m4 = *reinterpret_cast<const float4*>(m + (size_t)dst*4);
      float4 i4 = *reinterpret_cast<const float4*>(iden + (size_t)dst*4);
      E[100] = __expf(l4.x-m4.x)*i4.x;
      E[101] = __expf(l4.y-m4.y)*i4.y;
      E[102] = __expf(l4.z-m4.z)*i4.z;
      E[103] = __expf(l4.w-m4.w)*i4.w;
    }

    // ---- phase 1: w channels (lane c owns w[c], w[32+c], w[64+c], w[96+c]) ----
    float rr[16];
#pragma unroll
    for (int i=0;i<4;++i) *reinterpret_cast<float4*>(&rr[i*4]) =
        *reinterpret_cast<const float4*>(&E[80+i*4]);
    float wA=0.f, wB=0.f, wC=0.f, wD=0.f;
#pragma unroll
    for (int j4=0;j4<4;++j4){
      float4 a0 = *reinterpret_cast<const float4*>(&SH[OFF_RBF + c*16        + j4*4]);
      float4 a1 = *reinterpret_cast<const float4*>(&SH[OFF_RBF + (32+c)*16   + j4*4]);
      float4 a2 = *reinterpret_cast<const float4*>(&SH[OFF_RBF + (64+c)*16   + j4*4]);
      float4 a3 = *reinterpret_cast<const float4*>(&SH[OFF_RBF + (96+(c&15))*16 + j4*4]);
      float r0=rr[j4*4+0], r1=rr[j4*4+1], r2=rr[j4*4+2], r3=rr[j4*4+3];
      wA += r0*a0.x + r1*a0.y + r2*a0.z + r3*a0.w;
      wB += r0*a1.x + r1*a1.y + r2*a1.z + r3*a1.w;
      wC += r0*a2.x + r1*a2.y + r2*a2.z + r3*a2.w;
      wD += r0*a3.x + r1*a3.y + r2*a3.z + r3*a3.w;
    }

    // ---- phase 2: ms, t_, p, q ----
    const float y0=E[96], y1x=E[97], y1y=E[98], y1z=E[99];
    const float s_c = E[c];
    E[104+c] = wA * s_c * y0;       // ms[c]
    E[152+c] = wB * s_c;            // t_[c]
    if (c >= 16){
      int k = c-16;
      float vx=E[32+k*3], vy=E[33+k*3], vz=E[34+k*3];
      E[136+k] = wC * (vx*y1x+vy*y1y+vz*y1z) * IS3;  // ms[32+k] (wC = w[80+k])
    }
    if (c < 16){
      int k = c;
      float vx=E[32+k*3], vy=E[33+k*3], vz=E[34+k*3];
      float u = wC * y0;                             // w_vs[k]*y0
      E[200+k]    = u*vx; E[216+k] = u*vy; E[232+k] = u*vz;   // p[x][k]
      float cx=(vy*y1z - vz*y1y)*IS2;
      float cy=(vz*y1x - vx*y1z)*IS2;
      float cz=(vx*y1y - vy*y1x)*IS2;
      E[248+k]    = wD*cx; E[264+k] = wD*cy; E[280+k] = wD*cz; // q[x][k]
    }

    // ---- phase 3: sa[16] = t_ @ WvalvA ----
    if (c < 16){
      float acc=0.f;
#pragma unroll
      for (int k4=0;k4<8;++k4){
        float4 ww = *reinterpret_cast<const float4*>(&SH[OFF_VVA + c*32 + k4*4]);
        float4 tt = *reinterpret_cast<const float4*>(&E[152+k4*4]);
        acc += ww.x*tt.x + ww.y*tt.y + ww.z*tt.z + ww.w*tt.w;
      }
      E[184+c]=acc;
    }

    // ---- phase 4: vv (ungated). lane c -> l=c, and l=32+c for c<16 ----
    {
      int d0=c/3, x0=c-3*d0;
      float acc0 = E[184+d0]*E[97+x0];
#pragma unroll
      for (int k4=0;k4<4;++k4){
        float4 wb = *reinterpret_cast<const float4*>(&SH[OFF_VVB + d0*16 + k4*4]);
        float4 wc = *reinterpret_cast<const float4*>(&SH[OFF_VVC + d0*16 + k4*4]);
        float4 pp = *reinterpret_cast<const float4*>(&E[200 + x0*16 + k4*4]);
        float4 qq = *reinterpret_cast<const float4*>(&E[248 + x0*16 + k4*4]);
        acc0 += pp.x*wb.x+pp.y*wb.y+pp.z*wb.z+pp.w*wb.w
              + qq.x*wc.x+qq.y*wc.y+qq.z*wc.z+qq.w*wc.w;
      }
      E[344+c]=acc0;
      if (c < 16){
        int l=32+c, d1=l/3, x1=l-3*d1;
        float acc1 = E[184+d1]*E[97+x1];
#pragma unroll
        for (int k4=0;k4<4;++k4){
          float4 wb = *reinterpret_cast<const float4*>(&SH[OFF_VVB + d1*16 + k4*4]);
          float4 wc = *reinterpret_cast<const float4*>(&SH[OFF_VVC + d1*16 + k4*4]);
          float4 pp = *reinterpret_cast<const float4*>(&E[200 + x1*16 + k4*4]);
          float4 qq = *reinterpret_cast<const float4*>(&E[248 + x1*16 + k4*4]);
          acc1 += pp.x*wb.x+pp.y*wb.y+pp.z*wb.z+pp.w*wb.w
                + qq.x*wc.x+qq.y*wc.y+qq.z*wc.z+qq.w*wc.w;
        }
        E[344+l]=acc1;
      }
    }

    // ---- phase 5: vs[32] = ms @ Wvals ----
    float accv=0.f;
#pragma unroll
    for (int k4=0;k4<12;++k4){
      float4 ww = *reinterpret_cast<const float4*>(&SH[OFF_VALS + c*48 + k4*4]);
      float4 mm = *reinterpret_cast<const float4*>(&E[104+k4*4]);
      accv += ww.x*mm.x + ww.y*mm.y + ww.z*mm.z + ww.w*mm.w;
    }
    E[296+c]=accv;

    // ---- phase 6: gv[16] = sigm(vs_pre @ Wg) ----
    if (c < 16){
      float acc=0.f;
#pragma unroll
      for (int k4=0;k4<8;++k4){
        float4 ww = *reinterpret_cast<const float4*>(&SH[OFF_G + c*32 + k4*4]);
        float4 vv4 = *reinterpret_cast<const float4*>(&E[296+k4*4]);
        acc += ww.x*vv4.x + ww.y*vv4.y + ww.z*vv4.z + ww.w*vv4.w;
      }
      E[328+c]=sigm(acc);
    }

    // ---- phase 7: silu, gate vv, vs2, t2, p2, q2 ----
    const float vsc = accv * sigm(accv);
    E[152+c] = SH[OFF_W2+32+c]*vsc;        // t2
    E[104+c] = SH[OFF_W2+c]*vsc*y0;        // vs2[0:32] (overwrites ms)
    {
      int d0=c/3;
      E[344+c] = E[344+c]*E[328+d0];       // gate vv[l=c]
      if (c < 16){
        int l=32+c, d1=l/3;
        E[344+l] = E[344+l]*E[328+d1];     // gate vv[l=32+c]
      }
    }
    if (c >= 16){
      int k=c-16;
      float gx=E[344+k*3], gy=E[345+k*3], gz=E[346+k*3];
      E[136+k] = SH[OFF_W2+80+k]*(gx*y1x+gy*y1y+gz*y1z)*IS3;  // vs2[32+k]
    }
    if (c < 16){
      int k=c;
      float gx=E[344+k*3], gy=E[345+k*3], gz=E[346+k*3];
      float u = SH[OFF_W2+64+k]*y0;
      E[200+k]=u*gx; E[216+k]=u*gy; E[232+k]=u*gz;            // p2[x][k]
      float cx=(gy*y1z - gz*y1y)*IS2;
      float cy=(gz*y1x - gx*y1z)*IS2;
      float cz=(gx*y1y - gy*y1x)*IS2;
      float wq = SH[OFF_W2+96+k];
      E[248+k]=wq*cx; E[264+k]=wq*cy; E[280+k]=wq*cz;         // q2[x][k]
    }

    // ---- phase 8: flat_s[64] = vs2 @ Wvls, weighted store ----
    const float a0=E[100], a1=E[101], a2h=E[102], a3h=E[103];
    float* wrow = wflat + (size_t)pidx*160;
    {
      float f0=0.f, f1=0.f;
#pragma unroll
      for (int k4=0;k4<12;++k4){
        float4 v2 = *reinterpret_cast<const float4*>(&E[104+k4*4]);
        float4 w0 = *reinterpret_cast<const float4*>(&SH[OFF_VLS + c*48 + k4*4]);
        float4 w1 = *reinterpret_cast<const float4*>(&SH[OFF_VLS + (32+c)*48 + k4*4]);
        f0 += v2.x*w0.x + v2.y*w0.y + v2.z*w0.z + v2.w*w0.w;
        f1 += v2.x*w1.x + v2.y*w1.y + v2.z*w1.z + v2.w*w1.w;
      }
      wrow[c]    = f0*a0;
      wrow[32+c] = f1*((c<8)?a0:a1);
    }

    // ---- phase 9: flat_v[96], weighted store ----
    {
      float A2=0.f;
#pragma unroll
      for (int k4=0;k4<8;++k4){
        float4 ww = *reinterpret_cast<const float4*>(&SH[OFF_VLVA + c*32 + k4*4]);
        float4 tt = *reinterpret_cast<const float4*>(&E[152+k4*4]);
        A2 += ww.x*tt.x + ww.y*tt.y + ww.z*tt.z + ww.w*tt.w;
      }
      float b0=A2*y1x, b1=A2*y1y, b2=A2*y1z;
#pragma unroll
      for (int k4=0;k4<4;++k4){
        float4 wb = *reinterpret_cast<const float4*>(&SH[OFF_VLVB + c*16 + k4*4]);
        float4 wc = *reinterpret_cast<const float4*>(&SH[OFF_VLVC + c*16 + k4*4]);
        float4 p0 = *reinterpret_cast<const float4*>(&E[200 + k4*4]);
        float4 p1 = *reinterpret_cast<const float4*>(&E[216 + k4*4]);
        float4 p2v= *reinterpret_cast<const float4*>(&E[232 + k4*4]);
        float4 q0 = *reinterpret_cast<const float4*>(&E[248 + k4*4]);
        float4 q1 = *reinterpret_cast<const float4*>(&E[264 + k4*4]);
        float4 q2v= *reinterpret_cast<const float4*>(&E[280 + k4*4]);
        b0 += p0.x*wb.x+p0.y*wb.y+p0.z*wb.z+p0.w*wb.w + q0.x*wc.x+q0.y*wc.y+q0.z*wc.z+q0.w*wc.w;
        b1 += p1.x*wb.x+p1.y*wb.y+p1.z*wb.z+p1.w*wb.w + q1.x*wc.x+q1.y*wc.y+q1.z*wc.z+q1.w*wc.w;
        b2 += p2v.x*wb.x+p2v.y*wb.y+p2v.z*wb.z+p2v.w*wb.w + q2v.x*wc.x+q2v.y*wc.y+q2v.z*wc.z+q2v.w*wc.w;
      }
      int o = 64 + c*3;
      float aw0 = (o   < 80) ? a1 : ((o   < 120) ? a2h : a3h);
      float aw1 = (o+1 < 80) ? a1 : ((o+1 < 120) ? a2h : a3h);
      float aw2 = (o+2 < 80) ? a1 : ((o+2 < 120) ? a2h : a3h);
      wrow[o]   = b0*aw0;
      wrow[o+1] = b1*aw1;
      wrow[o+2] = b2*aw2;
    }
  }
}

// ------------- gather: per-dst sum of weighted per-edge rows ---------------
__global__ __launch_bounds__(256) void k_gather(
    const int* __restrict__ base, const int* __restrict__ deg,
    const float* __restrict__ wflat, float* __restrict__ agg)
{
  int id = blockIdx.x*256 + threadIdx.x;
  if (id >= NN*40) return;
  int d = id / 40, c = id % 40;
  int b = base[d], n = deg[d];
  float4 acc = make_float4(0.f,0.f,0.f,0.f);
  for (int i=0;i<n;++i){
    float4 w = reinterpret_cast<const float4*>(wflat + (size_t)(b+i)*160)[c];
    acc.x += w.x; acc.y += w.y; acc.z += w.z; acc.w += w.w;
  }
  reinterpret_cast<float4*>(agg + (size_t)d*160)[c] = acc;
}

// ------------- output pass: Wp projections + residual ----------------------
__global__ __launch_bounds__(256) void k_out(
    const float* __restrict__ node, const float* __restrict__ agg,
    const float* __restrict__ Wps, const float* __restrict__ Wpv,
    float* __restrict__ out)
{
  int n = blockIdx.x * 256 + threadIdx.x;
  if (n >= NN) return;
  const float* ar = agg + (size_t)n*160;
  const float* nr = node + (size_t)n*80;
  float* orow = out + (size_t)n*80;

  float a[64];
  { const float4* ap = reinterpret_cast<const float4*>(ar);
#pragma unroll
    for (int i=0;i<16;++i){ float4 t=ap[i];
      a[i*4]=t.x; a[i*4+1]=t.y; a[i*4+2]=t.z; a[i*4+3]=t.w; } }
#pragma unroll 1
  for (int d=0; d<32; ++d){
    float acc=0.f;
#pragma unroll
    for (int c=0;c<64;++c) acc += a[c]*Wps[c*32+d];
    orow[d] = nr[d] + acc;
  }
  float b[96];
  { const float4* bp = reinterpret_cast<const float4*>(ar + 64);
#pragma unroll
    for (int i=0;i<24;++i){ float4 t=bp[i];
      b[i*4]=t.x; b[i*4+1]=t.y; b[i*4+2]=t.z; b[i*4+3]=t.w; } }
#pragma unroll 1
  for (int d=0; d<16; ++d){
#pragma unroll
    for (int x=0;x<3;++x){
      float acc=0.f;
#pragma unroll
      for (int c=0;c<32;++c) acc += b[c*3+x]*Wpv[c*16+d];
      orow[32+d*3+x] = nr[32+d*3+x] + acc;
    }
  }
}

extern "C" void kernel_launch(void* const* d_in, const int* in_sizes, int n_in,
                              void* d_out, int out_size, void* d_ws, size_t ws_size,
                              hipStream_t stream)
{
  const float* node   = (const float*)d_in[0];
  const float* rbf    = (const float*)d_in[1];
  const float* rsh    = (const float*)d_in[2];
  const float* Wsrc_s = (const float*)d_in[3];
  const float* Wsrc_v = (const float*)d_in[4];
  const float* Wdst_s = (const float*)d_in[5];
  const float* Wdst_v = (const float*)d_in[6];
  const float* W_rbf  = (const float*)d_in[7];
  const float* dtp2   = (const float*)d_in[8];
  const float* Wa     = (const float*)d_in[9];
  const float* adot   = (const float*)d_in[10];
  const float* Wval_s = (const float*)d_in[11];
  const float* Wval_v = (const float*)d_in[12];
  const float* Wg     = (const float*)d_in[13];
  const float* Wvl_s  = (const float*)d_in[14];
  const float* Wvl_v  = (const float*)d_in[15];
  const float* Wp_s   = (const float*)d_in[16];
  const float* Wp_v   = (const float*)d_in[17];
  const int*   ei     = (const int*)d_in[18];

  float* ws = (float*)d_ws;

  size_t off = 0;
  float* ss   = ws + off; off += (size_t)NN*32;
  float* ds   = ws + off; off += (size_t)NN*32;
  float* sv   = ws + off; off += (size_t)NN*48;
  float* dv   = ws + off; off += (size_t)NN*48;
  float* lg   = ws + off; off += (size_t)EE*4;
  float* m    = ws + off; off += (size_t)NN*4;
  float* iden = ws + off; off += (size_t)NN*4;
  int* deg    = (int*)(ws + off); off += (size_t)NN;
  int* base   = (int*)(ws + off); off += (size_t)NN;
  int* cursor = (int*)(ws + off); off += (size_t)NN;
  int* csr    = (int*)(ws + off); off += (size_t)EE;
  float* agg  = ws + off; off += (size_t)NN*160;
  float* wflat= ws + off; off += (size_t)EE*160;
  size_t need_new = off * sizeof(float);
  if (ws_size < need_new) return;

  hipMemsetAsync(deg, 0, (size_t)NN*sizeof(int), stream);
  k_node   <<<NN/256, 256, 0, stream>>>(node, Wsrc_s, Wsrc_v, Wdst_s, Wdst_v, ss, ds, sv, dv);
  k_hist   <<<EE/256, 256, 0, stream>>>(ei, deg);
  k_scan   <<<1, 1024, 0, stream>>>(deg, base, cursor);
  k_scatter<<<EE/256, 256, 0, stream>>>(ei, cursor, csr);
  k_edgeA  <<<EE/256, 256, 0, stream>>>(ei, rbf, rsh, W_rbf, Wa, adot, ss, ds, sv, dv, lg);
  k_soft   <<<(NN*4)/256, 256, 0, stream>>>(base, deg, csr, lg, m, iden);
  k_edgeC3 <<<2048, 256, 0, stream>>>(csr, ei, rbf, rsh, W_rbf, Wval_s, Wval_v, Wg, Wvl_s,
                                      Wvl_v, dtp2, ss, ds, sv, dv, lg, m, iden, wflat);
  k_gather <<<(NN*40)/256, 256, 0, stream>>>(base, deg, wflat, agg);
  k_out    <<<NN/256, 256, 0, stream>>>(node, agg, Wp_s, Wp_v, (float*)d_out);
}

// Round 4
// 646.000 us; speedup vs baseline: 4.0305x; 1.2263x over previous
//
#include <hip/hip_runtime.h>

#define NN 32768
#define EE 262144

static __device__ __forceinline__ float sigm(float x){
  return 1.0f / (1.0f + __expf(-x));
}

// ---------------- node pass: o3-layernorm + src/dst linears ----------------
__global__ __launch_bounds__(256) void k_node(
    const float* __restrict__ node,
    const float* __restrict__ Wss, const float* __restrict__ Wsv,
    const float* __restrict__ Wds, const float* __restrict__ Wdv,
    float* __restrict__ ss, float* __restrict__ ds,
    float* __restrict__ sv, float* __restrict__ dv)
{
  int n = blockIdx.x * 256 + threadIdx.x;
  if (n >= NN) return;
  const float4* row = reinterpret_cast<const float4*>(node + (size_t)n * 80);
  float s[32], v[48];
#pragma unroll
  for (int i = 0; i < 8; ++i){
    float4 t = row[i];
    s[i*4+0]=t.x; s[i*4+1]=t.y; s[i*4+2]=t.z; s[i*4+3]=t.w;
  }
#pragma unroll
  for (int i = 0; i < 12; ++i){
    float4 t = row[8+i];
    v[i*4+0]=t.x; v[i*4+1]=t.y; v[i*4+2]=t.z; v[i*4+3]=t.w;
  }
  float mean = 0.f;
#pragma unroll
  for (int i=0;i<32;++i) mean += s[i];
  mean *= (1.0f/32.0f);
  float var = 0.f;
#pragma unroll
  for (int i=0;i<32;++i){ float d0 = s[i]-mean; var += d0*d0; }
  var *= (1.0f/32.0f);
  float sinv = rsqrtf(var + 1e-5f);
#pragma unroll
  for (int i=0;i<32;++i) s[i] = (s[i]-mean)*sinv;
  float n2 = 0.f;
#pragma unroll
  for (int i=0;i<48;++i) n2 += v[i]*v[i];
  n2 *= (1.0f/16.0f);
  float vinv = rsqrtf(n2 + 1e-5f);
#pragma unroll
  for (int i=0;i<48;++i) v[i] *= vinv;

  float* ssr = ss + (size_t)n*32;
  float* dsr = ds + (size_t)n*32;
#pragma unroll 1
  for (int d=0; d<32; ++d){
    float a=0.f, b=0.f;
#pragma unroll
    for (int c=0;c<32;++c){ a += s[c]*Wss[c*32+d]; b += s[c]*Wds[c*32+d]; }
    ssr[d]=a; dsr[d]=b;
  }
  float* svr = sv + (size_t)n*48;
  float* dvr = dv + (size_t)n*48;
#pragma unroll 1
  for (int d=0; d<16; ++d){
#pragma unroll
    for (int x=0;x<3;++x){
      float a=0.f, b=0.f;
#pragma unroll
      for (int c=0;c<16;++c){ a += v[c*3+x]*Wsv[c*16+d]; b += v[c*3+x]*Wdv[c*16+d]; }
      svr[d*3+x]=a; dvr[d*3+x]=b;
    }
  }
}

// ---------------- CSR build ----------------
__global__ __launch_bounds__(256) void k_hist(const int* __restrict__ ei, int* __restrict__ deg){
  int e = blockIdx.x*256 + threadIdx.x;
  if (e >= EE) return;
  atomicAdd(deg + ei[EE + e], 1);
}

__global__ __launch_bounds__(1024) void k_scan(const int* __restrict__ deg,
                                               int* __restrict__ base, int* __restrict__ cursor){
  __shared__ int lds[1024];
  int t = threadIdx.x;
  int v[32];
#pragma unroll
  for (int i=0;i<32;++i) v[i] = deg[t*32+i];
  int run = 0;
#pragma unroll
  for (int i=0;i<32;++i){ int x=v[i]; v[i]=run; run+=x; }
  lds[t]=run; __syncthreads();
  for (int off=1; off<1024; off<<=1){
    int add = (t>=off) ? lds[t-off] : 0;
    __syncthreads();
    lds[t] += add;
    __syncthreads();
  }
  int pre = (t==0) ? 0 : lds[t-1];
#pragma unroll
  for (int i=0;i<32;++i){ int b = pre + v[i]; base[t*32+i]=b; cursor[t*32+i]=b; }
}

__global__ __launch_bounds__(256) void k_scatter(const int* __restrict__ ei,
                                                 int* __restrict__ cursor, int* __restrict__ csr){
  int e = blockIdx.x*256 + threadIdx.x;
  if (e >= EE) return;
  int d = ei[EE + e];
  int pos = atomicAdd(cursor + d, 1);
  csr[pos] = e;
}

// ============== cooperative edge pass A: attention logits ==================
// 32 lanes per edge, 16 edge-groups per 512-thread block.
// LDS (floats): RBFA[32][20] rows 0..31 of Wrbf^T; RBFD[16][20] rows 80..95;
//               WA[64][52]; ADOT[64]; per-edge E stride 152.
#define A_RBFA 0
#define A_RBFD 640
#define A_WA   960
#define A_ADOT 4288
#define A_EDG  4352
#define A_ESTR 152
// E layout: 0:s_[32] 32:v_[48] 80:r[16] 96:y[4] 104:ms[48]

__global__ __launch_bounds__(512) void k_edgeA2(
    const int* __restrict__ ei,
    const float* __restrict__ rbf, const float* __restrict__ rsh,
    const float* __restrict__ Wrbf, const float* __restrict__ Wa,
    const float* __restrict__ adot,
    const float* __restrict__ ss, const float* __restrict__ ds,
    const float* __restrict__ sv, const float* __restrict__ dv,
    float* __restrict__ logits)
{
  __shared__ __align__(16) float SH[A_EDG + 16*A_ESTR];
  const int t = threadIdx.x;
  for (int i=t; i<32*16; i+=512){ int row=i>>4, j=i&15; SH[A_RBFA+row*20+j] = Wrbf[j*112+row]; }
  for (int i=t; i<16*16; i+=512){ int row=i>>4, j=i&15; SH[A_RBFD+row*20+j] = Wrbf[j*112+80+row]; }
  for (int i=t; i<64*48; i+=512){ int o=i/48, k=i-48*o; SH[A_WA+o*52+k] = Wa[k*64+o]; }
  for (int i=t; i<64;    i+=512){ SH[A_ADOT+i] = adot[i]; }
  __syncthreads();

  const int g = t >> 5;
  const int c = t & 31;
  float* E = &SH[A_EDG + g*A_ESTR];
  const float IS3 = 0.57735026918962576f;

#pragma unroll 1
  for (int tile=0; tile<16; ++tile){
    const int e = blockIdx.x*256 + tile*16 + g;
    const int src = ei[e], dst = ei[EE + e];

    // phase 0: stage edge data
    if (c < 8){
      float4 a = *reinterpret_cast<const float4*>(ss + (size_t)src*32 + c*4);
      float4 b = *reinterpret_cast<const float4*>(ds + (size_t)dst*32 + c*4);
      float4 o; o.x=a.x+b.x; o.y=a.y+b.y; o.z=a.z+b.z; o.w=a.w+b.w;
      *reinterpret_cast<float4*>(&E[c*4]) = o;
    } else if (c < 20){
      int i = c-8;
      float4 a = *reinterpret_cast<const float4*>(sv + (size_t)src*48 + i*4);
      float4 b = *reinterpret_cast<const float4*>(dv + (size_t)dst*48 + i*4);
      float4 o; o.x=a.x+b.x; o.y=a.y+b.y; o.z=a.z+b.z; o.w=a.w+b.w;
      *reinterpret_cast<float4*>(&E[32+i*4]) = o;
    } else if (c < 24){
      int i = c-20;
      *reinterpret_cast<float4*>(&E[80+i*4]) =
          *reinterpret_cast<const float4*>(rbf + (size_t)e*16 + i*4);
    } else if (c == 24){
      *reinterpret_cast<float4*>(&E[96]) =
          *reinterpret_cast<const float4*>(rsh + (size_t)e*4);
    }

    // phase 1: ms[48]
    float rr[16];
#pragma unroll
    for (int i=0;i<4;++i) *reinterpret_cast<float4*>(&rr[i*4]) =
        *reinterpret_cast<const float4*>(&E[80+i*4]);
    const float y0=E[96], y1x=E[97], y1y=E[98], y1z=E[99];
    {
      float wA=0.f;
#pragma unroll
      for (int j4=0;j4<4;++j4){
        float4 a0 = *reinterpret_cast<const float4*>(&SH[A_RBFA + c*20 + j4*4]);
        wA += rr[j4*4+0]*a0.x + rr[j4*4+1]*a0.y + rr[j4*4+2]*a0.z + rr[j4*4+3]*a0.w;
      }
      E[104+c] = wA * E[c] * y0;
    }
    if (c < 16){
      float wD=0.f;
#pragma unroll
      for (int j4=0;j4<4;++j4){
        float4 a0 = *reinterpret_cast<const float4*>(&SH[A_RBFD + c*20 + j4*4]);
        wD += rr[j4*4+0]*a0.x + rr[j4*4+1]*a0.y + rr[j4*4+2]*a0.z + rr[j4*4+3]*a0.w;
      }
      float vx=E[32+c*3], vy=E[33+c*3], vz=E[34+c*3];
      E[136+c] = wD * (vx*y1x + vy*y1y + vz*y1z) * IS3;
    }

    // phase 2: per-lane o=c and o=32+c, then per-head shuffle reduce
    float mm[48];
#pragma unroll
    for (int k4=0;k4<12;++k4) *reinterpret_cast<float4*>(&mm[k4*4]) =
        *reinterpret_cast<const float4*>(&E[104+k4*4]);
    float acc0=0.f, acc1=0.f;
#pragma unroll
    for (int k4=0;k4<12;++k4){
      float4 w0 = *reinterpret_cast<const float4*>(&SH[A_WA + c*52 + k4*4]);
      float4 w1 = *reinterpret_cast<const float4*>(&SH[A_WA + (32+c)*52 + k4*4]);
      acc0 += mm[k4*4+0]*w0.x + mm[k4*4+1]*w0.y + mm[k4*4+2]*w0.z + mm[k4*4+3]*w0.w;
      acc1 += mm[k4*4+0]*w1.x + mm[k4*4+1]*w1.y + mm[k4*4+2]*w1.z + mm[k4*4+3]*w1.w;
    }
    acc0 = ((acc0 > 0.f) ? acc0 : 0.2f*acc0) * SH[A_ADOT+c];
    acc1 = ((acc1 > 0.f) ? acc1 : 0.2f*acc1) * SH[A_ADOT+32+c];
#pragma unroll
    for (int msk=8; msk>=1; msk>>=1){
      acc0 += __shfl_xor(acc0, msk);
      acc1 += __shfl_xor(acc1, msk);
    }
    if ((c & 15) == 0){
      int h0 = c >> 4;                 // 0 or 1
      logits[(size_t)e*4 + h0]     = acc0;   // heads 0,1
      logits[(size_t)e*4 + 2 + h0] = acc1;   // heads 2,3
    }
  }
}

// ------------- per-(dst,head) softmax stats via CSR (no atomics) ----------
__global__ __launch_bounds__(256) void k_soft(
    const int* __restrict__ base, const int* __restrict__ deg,
    const int* __restrict__ csr, const float* __restrict__ logits,
    float* __restrict__ m, float* __restrict__ iden)
{
  int id = blockIdx.x*256 + threadIdx.x;
  if (id >= NN*4) return;
  int d = id >> 2, h = id & 3;
  int b = base[d], n = deg[d];
  float mm = -3.4e38f;
  for (int i=0;i<n;++i){ int e = csr[b+i]; mm = fmaxf(mm, logits[(size_t)e*4+h]); }
  float s = 0.f;
  for (int i=0;i<n;++i){ int e = csr[b+i]; s += __expf(logits[(size_t)e*4+h] - mm); }
  m[id] = mm;
  iden[id] = (n>0) ? 1.0f/s : 0.f;
}

// ===================== cooperative edge value pass =========================
// 32 lanes/edge, 16 groups per 512-thread block. Transposed weights in LDS
// with +4 padded strides (16->20, 32->36, 48->52) to cut bank conflicts
// from 16-way to 4-way.
#define OFF_RBF   0      // [112][20]
#define OFF_VALS  2240   // [32][52]
#define OFF_VVA   3904   // [16][36]
#define OFF_VVB   4480   // [16][20]
#define OFF_VVC   4800   // [16][20]
#define OFF_G     5120   // [16][36]
#define OFF_VLS   5696   // [64][52]
#define OFF_VLVA  9024   // [32][36]
#define OFF_VLVB  10176  // [32][20]
#define OFF_VLVC  10816  // [32][20]
#define OFF_W2    11456  // [112]
#define EDGOFF    11568
#define ESTRIDE   400
// per-edge scratch layout (floats, relative):
//   0: s_[32]   32: v_[48]   80: r[16]   96: y[4]   100: a[4]
// 104: ms[48]/vs2[48]  152: t_[32]/t2[32]  184: sa[16]
// 200: p[3][16]/p2[3][16]  248: q[3][16]/q2[3][16]
// 296: vs[32]  328: gv[16]  344: vv[48]

__global__ __launch_bounds__(512) void k_edgeC3(
    const int* __restrict__ csr, const int* __restrict__ ei,
    const float* __restrict__ rbf, const float* __restrict__ rsh,
    const float* __restrict__ Wrbf,
    const float* __restrict__ Wvals, const float* __restrict__ Wvalv,
    const float* __restrict__ Wg, const float* __restrict__ Wvls,
    const float* __restrict__ Wvlv, const float* __restrict__ w2,
    const float* __restrict__ ss, const float* __restrict__ ds,
    const float* __restrict__ sv, const float* __restrict__ dv,
    const float* __restrict__ logits, const float* __restrict__ m,
    const float* __restrict__ iden, float* __restrict__ wflat)
{
  __shared__ __align__(16) float SH[EDGOFF + 16*ESTRIDE];
  const int t = threadIdx.x;
  for (int i=t; i<112*16; i+=512){ int d=i>>4, k=i&15; SH[OFF_RBF+d*20+k]  = Wrbf[k*112+d]; }
  for (int i=t; i<32*48;  i+=512){ int d=i/48, k=i-48*d; SH[OFF_VALS+d*52+k] = Wvals[k*32+d]; }
  for (int i=t; i<16*32;  i+=512){ int d=i>>5, k=i&31; SH[OFF_VVA+d*36+k]  = Wvalv[k*16+d]; }
  for (int i=t; i<16*16;  i+=512){ int d=i>>4, k=i&15; SH[OFF_VVB+d*20+k]  = Wvalv[(32+k)*16+d]; }
  for (int i=t; i<16*16;  i+=512){ int d=i>>4, k=i&15; SH[OFF_VVC+d*20+k]  = Wvalv[(48+k)*16+d]; }
  for (int i=t; i<16*32;  i+=512){ int d=i>>5, k=i&31; SH[OFF_G+d*36+k]    = Wg[k*16+d]; }
  for (int i=t; i<64*48;  i+=512){ int d=i/48, k=i-48*d; SH[OFF_VLS+d*52+k] = Wvls[k*64+d]; }
  for (int i=t; i<32*32;  i+=512){ int d=i>>5, k=i&31; SH[OFF_VLVA+d*36+k] = Wvlv[k*32+d]; }
  for (int i=t; i<32*16;  i+=512){ int d=i>>4, k=i&15; SH[OFF_VLVB+d*20+k] = Wvlv[(32+k)*32+d]; }
  for (int i=t; i<32*16;  i+=512){ int d=i>>4, k=i&15; SH[OFF_VLVC+d*20+k] = Wvlv[(48+k)*32+d]; }
  for (int i=t; i<112;    i+=512){ SH[OFF_W2+i] = w2[i]; }
  __syncthreads();

  const int g = t >> 5;
  const int c = t & 31;
  float* E = &SH[EDGOFF + g*ESTRIDE];
  const float IS3 = 0.57735026918962576f;
  const float IS2 = 0.70710678118654752f;

#pragma unroll 1
  for (int tile=0; tile<16; ++tile){
    const int pidx = blockIdx.x*256 + tile*16 + g;
    const int e = csr[pidx];
    const int src = ei[e], dst = ei[EE + e];

    // ---- phase 0: load edge data into LDS ----
    if (c < 8){
      float4 a = *reinterpret_cast<const float4*>(ss + (size_t)src*32 + c*4);
      float4 b = *reinterpret_cast<const float4*>(ds + (size_t)dst*32 + c*4);
      float4 o; o.x=a.x+b.x; o.y=a.y+b.y; o.z=a.z+b.z; o.w=a.w+b.w;
      *reinterpret_cast<float4*>(&E[c*4]) = o;
    } else if (c < 20){
      int i = c-8;
      float4 a = *reinterpret_cast<const float4*>(sv + (size_t)src*48 + i*4);
      float4 b = *reinterpret_cast<const float4*>(dv + (size_t)dst*48 + i*4);
      float4 o; o.x=a.x+b.x; o.y=a.y+b.y; o.z=a.z+b.z; o.w=a.w+b.w;
      *reinterpret_cast<float4*>(&E[32+i*4]) = o;
    } else if (c < 24){
      int i = c-20;
      *reinterpret_cast<float4*>(&E[80+i*4]) =
          *reinterpret_cast<const float4*>(rbf + (size_t)e*16 + i*4);
    } else if (c == 24){
      *reinterpret_cast<float4*>(&E[96]) =
          *reinterpret_cast<const float4*>(rsh + (size_t)e*4);
    } else if (c == 25){
      float4 l4 = *reinterpret_cast<const float4*>(logits + (size_t)e*4);
      float4 m4 = *reinterpret_cast<const float4*>(m + (size_t)dst*4);
      float4 i4 = *reinterpret_cast<const float4*>(iden + (size_t)dst*4);
      E[100] = __expf(l4.x-m4.x)*i4.x;
      E[101] = __expf(l4.y-m4.y)*i4.y;
      E[102] = __expf(l4.z-m4.z)*i4.z;
      E[103] = __expf(l4.w-m4.w)*i4.w;
    }

    // ---- phase 1: w channels ----
    float rr[16];
#pragma unroll
    for (int i=0;i<4;++i) *reinterpret_cast<float4*>(&rr[i*4]) =
        *reinterpret_cast<const float4*>(&E[80+i*4]);
    float wA=0.f, wB=0.f, wC=0.f, wD=0.f;
#pragma unroll
    for (int j4=0;j4<4;++j4){
      float4 a0 = *reinterpret_cast<const float4*>(&SH[OFF_RBF + c*20          + j4*4]);
      float4 a1 = *reinterpret_cast<const float4*>(&SH[OFF_RBF + (32+c)*20     + j4*4]);
      float4 a2 = *reinterpret_cast<const float4*>(&SH[OFF_RBF + (64+c)*20     + j4*4]);
      float4 a3 = *reinterpret_cast<const float4*>(&SH[OFF_RBF + (96+(c&15))*20 + j4*4]);
      float r0=rr[j4*4+0], r1=rr[j4*4+1], r2=rr[j4*4+2], r3=rr[j4*4+3];
      wA += r0*a0.x + r1*a0.y + r2*a0.z + r3*a0.w;
      wB += r0*a1.x + r1*a1.y + r2*a1.z + r3*a1.w;
      wC += r0*a2.x + r1*a2.y + r2*a2.z + r3*a2.w;
      wD += r0*a3.x + r1*a3.y + r2*a3.z + r3*a3.w;
    }

    // ---- phase 2: ms, t_, p, q ----
    const float y0=E[96], y1x=E[97], y1y=E[98], y1z=E[99];
    const float s_c = E[c];
    E[104+c] = wA * s_c * y0;
    E[152+c] = wB * s_c;
    if (c >= 16){
      int k = c-16;
      float vx=E[32+k*3], vy=E[33+k*3], vz=E[34+k*3];
      E[136+k] = wC * (vx*y1x+vy*y1y+vz*y1z) * IS3;
    }
    if (c < 16){
      int k = c;
      float vx=E[32+k*3], vy=E[33+k*3], vz=E[34+k*3];
      float u = wC * y0;
      E[200+k]    = u*vx; E[216+k] = u*vy; E[232+k] = u*vz;
      float cx=(vy*y1z - vz*y1y)*IS2;
      float cy=(vz*y1x - vx*y1z)*IS2;
      float cz=(vx*y1y - vy*y1x)*IS2;
      E[248+k]    = wD*cx; E[264+k] = wD*cy; E[280+k] = wD*cz;
    }

    // ---- phase 3: sa[16] = t_ @ WvalvA ----
    if (c < 16){
      float acc=0.f;
#pragma unroll
      for (int k4=0;k4<8;++k4){
        float4 ww = *reinterpret_cast<const float4*>(&SH[OFF_VVA + c*36 + k4*4]);
        float4 tt = *reinterpret_cast<const float4*>(&E[152+k4*4]);
        acc += ww.x*tt.x + ww.y*tt.y + ww.z*tt.z + ww.w*tt.w;
      }
      E[184+c]=acc;
    }

    // ---- phase 4: vv (ungated) ----
    {
      int d0=c/3, x0=c-3*d0;
      float acc0 = E[184+d0]*E[97+x0];
#pragma unroll
      for (int k4=0;k4<4;++k4){
        float4 wb = *reinterpret_cast<const float4*>(&SH[OFF_VVB + d0*20 + k4*4]);
        float4 wc = *reinterpret_cast<const float4*>(&SH[OFF_VVC + d0*20 + k4*4]);
        float4 pp = *reinterpret_cast<const float4*>(&E[200 + x0*16 + k4*4]);
        float4 qq = *reinterpret_cast<const float4*>(&E[248 + x0*16 + k4*4]);
        acc0 += pp.x*wb.x+pp.y*wb.y+pp.z*wb.z+pp.w*wb.w
              + qq.x*wc.x+qq.y*wc.y+qq.z*wc.z+qq.w*wc.w;
      }
      E[344+c]=acc0;
      if (c < 16){
        int l=32+c, d1=l/3, x1=l-3*d1;
        float acc1 = E[184+d1]*E[97+x1];
#pragma unroll
        for (int k4=0;k4<4;++k4){
          float4 wb = *reinterpret_cast<const float4*>(&SH[OFF_VVB + d1*20 + k4*4]);
          float4 wc = *reinterpret_cast<const float4*>(&SH[OFF_VVC + d1*20 + k4*4]);
          float4 pp = *reinterpret_cast<const float4*>(&E[200 + x1*16 + k4*4]);
          float4 qq = *reinterpret_cast<const float4*>(&E[248 + x1*16 + k4*4]);
          acc1 += pp.x*wb.x+pp.y*wb.y+pp.z*wb.z+pp.w*wb.w
                + qq.x*wc.x+qq.y*wc.y+qq.z*wc.z+qq.w*wc.w;
        }
        E[344+l]=acc1;
      }
    }

    // ---- phase 5: vs[32] = ms @ Wvals ----
    float accv=0.f;
#pragma unroll
    for (int k4=0;k4<12;++k4){
      float4 ww = *reinterpret_cast<const float4*>(&SH[OFF_VALS + c*52 + k4*4]);
      float4 mm = *reinterpret_cast<const float4*>(&E[104+k4*4]);
      accv += ww.x*mm.x + ww.y*mm.y + ww.z*mm.z + ww.w*mm.w;
    }
    E[296+c]=accv;

    // ---- phase 6: gv[16] ----
    if (c < 16){
      float acc=0.f;
#pragma unroll
      for (int k4=0;k4<8;++k4){
        float4 ww = *reinterpret_cast<const float4*>(&SH[OFF_G + c*36 + k4*4]);
        float4 vv4 = *reinterpret_cast<const float4*>(&E[296+k4*4]);
        acc += ww.x*vv4.x + ww.y*vv4.y + ww.z*vv4.z + ww.w*vv4.w;
      }
      E[328+c]=sigm(acc);
    }

    // ---- phase 7: silu, gate vv, vs2, t2, p2, q2 ----
    const float vsc = accv * sigm(accv);
    E[152+c] = SH[OFF_W2+32+c]*vsc;
    E[104+c] = SH[OFF_W2+c]*vsc*y0;
    {
      int d0=c/3;
      E[344+c] = E[344+c]*E[328+d0];
      if (c < 16){
        int l=32+c, d1=l/3;
        E[344+l] = E[344+l]*E[328+d1];
      }
    }
    if (c >= 16){
      int k=c-16;
      float gx=E[344+k*3], gy=E[345+k*3], gz=E[346+k*3];
      E[136+k] = SH[OFF_W2+80+k]*(gx*y1x+gy*y1y+gz*y1z)*IS3;
    }
    if (c < 16){
      int k=c;
      float gx=E[344+k*3], gy=E[345+k*3], gz=E[346+k*3];
      float u = SH[OFF_W2+64+k]*y0;
      E[200+k]=u*gx; E[216+k]=u*gy; E[232+k]=u*gz;
      float cx=(gy*y1z - gz*y1y)*IS2;
      float cy=(gz*y1x - gx*y1z)*IS2;
      float cz=(gx*y1y - gy*y1x)*IS2;
      float wq = SH[OFF_W2+96+k];
      E[248+k]=wq*cx; E[264+k]=wq*cy; E[280+k]=wq*cz;
    }

    // ---- phase 8: flat_s[64] = vs2 @ Wvls, weighted store ----
    const float a0=E[100], a1=E[101], a2h=E[102], a3h=E[103];
    float* wrow = wflat + (size_t)pidx*160;
    {
      float f0=0.f, f1=0.f;
#pragma unroll
      for (int k4=0;k4<12;++k4){
        float4 v2 = *reinterpret_cast<const float4*>(&E[104+k4*4]);
        float4 w0 = *reinterpret_cast<const float4*>(&SH[OFF_VLS + c*52 + k4*4]);
        float4 w1 = *reinterpret_cast<const float4*>(&SH[OFF_VLS + (32+c)*52 + k4*4]);
        f0 += v2.x*w0.x + v2.y*w0.y + v2.z*w0.z + v2.w*w0.w;
        f1 += v2.x*w1.x + v2.y*w1.y + v2.z*w1.z + v2.w*w1.w;
      }
      wrow[c]    = f0*a0;
      wrow[32+c] = f1*((c<8)?a0:a1);
    }

    // ---- phase 9: flat_v[96], weighted store ----
    {
      float A2=0.f;
#pragma unroll
      for (int k4=0;k4<8;++k4){
        float4 ww = *reinterpret_cast<const float4*>(&SH[OFF_VLVA + c*36 + k4*4]);
        float4 tt = *reinterpret_cast<const float4*>(&E[152+k4*4]);
        A2 += ww.x*tt.x + ww.y*tt.y + ww.z*tt.z + ww.w*tt.w;
      }
      float b0=A2*y1x, b1=A2*y1y, b2=A2*y1z;
#pragma unroll
      for (int k4=0;k4<4;++k4){
        float4 wb = *reinterpret_cast<const float4*>(&SH[OFF_VLVB + c*20 + k4*4]);
        float4 wc = *reinterpret_cast<const float4*>(&SH[OFF_VLVC + c*20 + k4*4]);
        float4 p0 = *reinterpret_cast<const float4*>(&E[200 + k4*4]);
        float4 p1 = *reinterpret_cast<const float4*>(&E[216 + k4*4]);
        float4 p2v= *reinterpret_cast<const float4*>(&E[232 + k4*4]);
        float4 q0 = *reinterpret_cast<const float4*>(&E[248 + k4*4]);
        float4 q1 = *reinterpret_cast<const float4*>(&E[264 + k4*4]);
        float4 q2v= *reinterpret_cast<const float4*>(&E[280 + k4*4]);
        b0 += p0.x*wb.x+p0.y*wb.y+p0.z*wb.z+p0.w*wb.w + q0.x*wc.x+q0.y*wc.y+q0.z*wc.z+q0.w*wc.w;
        b1 += p1.x*wb.x+p1.y*wb.y+p1.z*wb.z+p1.w*wb.w + q1.x*wc.x+q1.y*wc.y+q1.z*wc.z+q1.w*wc.w;
        b2 += p2v.x*wb.x+p2v.y*wb.y+p2v.z*wb.z+p2v.w*wb.w + q2v.x*wc.x+q2v.y*wc.y+q2v.z*wc.z+q2v.w*wc.w;
      }
      int o = 64 + c*3;
      float aw0 = (o   < 80) ? a1 : ((o   < 120) ? a2h : a3h);
      float aw1 = (o+1 < 80) ? a1 : ((o+1 < 120) ? a2h : a3h);
      float aw2 = (o+2 < 80) ? a1 : ((o+2 < 120) ? a2h : a3h);
      wrow[o]   = b0*aw0;
      wrow[o+1] = b1*aw1;
      wrow[o+2] = b2*aw2;
    }
  }
}

// ------------- gather: per-dst sum of weighted per-edge rows ---------------
__global__ __launch_bounds__(256) void k_gather(
    const int* __restrict__ base, const int* __restrict__ deg,
    const float* __restrict__ wflat, float* __restrict__ agg)
{
  int id = blockIdx.x*256 + threadIdx.x;
  if (id >= NN*40) return;
  int d = id / 40, c = id % 40;
  int b = base[d], n = deg[d];
  float4 acc = make_float4(0.f,0.f,0.f,0.f);
  for (int i=0;i<n;++i){
    float4 w = reinterpret_cast<const float4*>(wflat + (size_t)(b+i)*160)[c];
    acc.x += w.x; acc.y += w.y; acc.z += w.z; acc.w += w.w;
  }
  reinterpret_cast<float4*>(agg + (size_t)d*160)[c] = acc;
}

// ------------- output pass: Wp projections + residual ----------------------
__global__ __launch_bounds__(256) void k_out(
    const float* __restrict__ node, const float* __restrict__ agg,
    const float* __restrict__ Wps, const float* __restrict__ Wpv,
    float* __restrict__ out)
{
  int n = blockIdx.x * 256 + threadIdx.x;
  if (n >= NN) return;
  const float* ar = agg + (size_t)n*160;
  const float* nr = node + (size_t)n*80;
  float* orow = out + (size_t)n*80;

  float a[64];
  { const float4* ap = reinterpret_cast<const float4*>(ar);
#pragma unroll
    for (int i=0;i<16;++i){ float4 t=ap[i];
      a[i*4]=t.x; a[i*4+1]=t.y; a[i*4+2]=t.z; a[i*4+3]=t.w; } }
#pragma unroll 1
  for (int d=0; d<32; ++d){
    float acc=0.f;
#pragma unroll
    for (int c=0;c<64;++c) acc += a[c]*Wps[c*32+d];
    orow[d] = nr[d] + acc;
  }
  float b[96];
  { const float4* bp = reinterpret_cast<const float4*>(ar + 64);
#pragma unroll
    for (int i=0;i<24;++i){ float4 t=bp[i];
      b[i*4]=t.x; b[i*4+1]=t.y; b[i*4+2]=t.z; b[i*4+3]=t.w; } }
#pragma unroll 1
  for (int d=0; d<16; ++d){
#pragma unroll
    for (int x=0;x<3;++x){
      float acc=0.f;
#pragma unroll
      for (int c=0;c<32;++c) acc += b[c*3+x]*Wpv[c*16+d];
      orow[32+d*3+x] = nr[32+d*3+x] + acc;
    }
  }
}

extern "C" void kernel_launch(void* const* d_in, const int* in_sizes, int n_in,
                              void* d_out, int out_size, void* d_ws, size_t ws_size,
                              hipStream_t stream)
{
  const float* node   = (const float*)d_in[0];
  const float* rbf    = (const float*)d_in[1];
  const float* rsh    = (const float*)d_in[2];
  const float* Wsrc_s = (const float*)d_in[3];
  const float* Wsrc_v = (const float*)d_in[4];
  const float* Wdst_s = (const float*)d_in[5];
  const float* Wdst_v = (const float*)d_in[6];
  const float* W_rbf  = (const float*)d_in[7];
  const float* dtp2   = (const float*)d_in[8];
  const float* Wa     = (const float*)d_in[9];
  const float* adot   = (const float*)d_in[10];
  const float* Wval_s = (const float*)d_in[11];
  const float* Wval_v = (const float*)d_in[12];
  const float* Wg     = (const float*)d_in[13];
  const float* Wvl_s  = (const float*)d_in[14];
  const float* Wvl_v  = (const float*)d_in[15];
  const float* Wp_s   = (const float*)d_in[16];
  const float* Wp_v   = (const float*)d_in[17];
  const int*   ei     = (const int*)d_in[18];

  float* ws = (float*)d_ws;

  size_t off = 0;
  float* ss   = ws + off; off += (size_t)NN*32;
  float* ds   = ws + off; off += (size_t)NN*32;
  float* sv   = ws + off; off += (size_t)NN*48;
  float* dv   = ws + off; off += (size_t)NN*48;
  float* lg   = ws + off; off += (size_t)EE*4;
  float* m    = ws + off; off += (size_t)NN*4;
  float* iden = ws + off; off += (size_t)NN*4;
  int* deg    = (int*)(ws + off); off += (size_t)NN;
  int* base   = (int*)(ws + off); off += (size_t)NN;
  int* cursor = (int*)(ws + off); off += (size_t)NN;
  int* csr    = (int*)(ws + off); off += (size_t)EE;
  float* agg  = ws + off; off += (size_t)NN*160;
  float* wflat= ws + off; off += (size_t)EE*160;
  size_t need_new = off * sizeof(float);
  if (ws_size < need_new) return;

  hipMemsetAsync(deg, 0, (size_t)NN*sizeof(int), stream);
  k_node   <<<NN/256, 256, 0, stream>>>(node, Wsrc_s, Wsrc_v, Wdst_s, Wdst_v, ss, ds, sv, dv);
  k_hist   <<<EE/256, 256, 0, stream>>>(ei, deg);
  k_scan   <<<1, 1024, 0, stream>>>(deg, base, cursor);
  k_scatter<<<EE/256, 256, 0, stream>>>(ei, cursor, csr);
  k_edgeA2 <<<EE/256, 512, 0, stream>>>(ei, rbf, rsh, W_rbf, Wa, adot, ss, ds, sv, dv, lg);
  k_soft   <<<(NN*4)/256, 256, 0, stream>>>(base, deg, csr, lg, m, iden);
  k_edgeC3 <<<EE/256, 512, 0, stream>>>(csr, ei, rbf, rsh, W_rbf, Wval_s, Wval_v, Wg, Wvl_s,
                                        Wvl_v, dtp2, ss, ds, sv, dv, lg, m, iden, wflat);
  k_gather <<<(NN*40)/256, 256, 0, stream>>>(base, deg, wflat, agg);
  k_out    <<<NN/256, 256, 0, stream>>>(node, agg, Wp_s, Wp_v, (float*)d_out);
}

// Round 5
// 577.497 us; speedup vs baseline: 4.5086x; 1.1186x over previous
//
#include <hip/hip_runtime.h>

#define NN 32768
#define EE 262144

static __device__ __forceinline__ float sigm(float x){
  return 1.0f / (1.0f + __expf(-x));
}

// ---------------- node pass: o3-layernorm + src/dst linears ----------------
__global__ __launch_bounds__(256) void k_node(
    const float* __restrict__ node,
    const float* __restrict__ Wss, const float* __restrict__ Wsv,
    const float* __restrict__ Wds, const float* __restrict__ Wdv,
    float* __restrict__ ss, float* __restrict__ ds,
    float* __restrict__ sv, float* __restrict__ dv)
{
  int n = blockIdx.x * 256 + threadIdx.x;
  if (n >= NN) return;
  const float4* row = reinterpret_cast<const float4*>(node + (size_t)n * 80);
  float s[32], v[48];
#pragma unroll
  for (int i = 0; i < 8; ++i){
    float4 t = row[i];
    s[i*4+0]=t.x; s[i*4+1]=t.y; s[i*4+2]=t.z; s[i*4+3]=t.w;
  }
#pragma unroll
  for (int i = 0; i < 12; ++i){
    float4 t = row[8+i];
    v[i*4+0]=t.x; v[i*4+1]=t.y; v[i*4+2]=t.z; v[i*4+3]=t.w;
  }
  float mean = 0.f;
#pragma unroll
  for (int i=0;i<32;++i) mean += s[i];
  mean *= (1.0f/32.0f);
  float var = 0.f;
#pragma unroll
  for (int i=0;i<32;++i){ float d0 = s[i]-mean; var += d0*d0; }
  var *= (1.0f/32.0f);
  float sinv = rsqrtf(var + 1e-5f);
#pragma unroll
  for (int i=0;i<32;++i) s[i] = (s[i]-mean)*sinv;
  float n2 = 0.f;
#pragma unroll
  for (int i=0;i<48;++i) n2 += v[i]*v[i];
  n2 *= (1.0f/16.0f);
  float vinv = rsqrtf(n2 + 1e-5f);
#pragma unroll
  for (int i=0;i<48;++i) v[i] *= vinv;

  float* ssr = ss + (size_t)n*32;
  float* dsr = ds + (size_t)n*32;
#pragma unroll 1
  for (int d=0; d<32; ++d){
    float a=0.f, b=0.f;
#pragma unroll
    for (int c=0;c<32;++c){ a += s[c]*Wss[c*32+d]; b += s[c]*Wds[c*32+d]; }
    ssr[d]=a; dsr[d]=b;
  }
  float* svr = sv + (size_t)n*48;
  float* dvr = dv + (size_t)n*48;
#pragma unroll 1
  for (int d=0; d<16; ++d){
#pragma unroll
    for (int x=0;x<3;++x){
      float a=0.f, b=0.f;
#pragma unroll
      for (int c=0;c<16;++c){ a += v[c*3+x]*Wsv[c*16+d]; b += v[c*3+x]*Wdv[c*16+d]; }
      svr[d*3+x]=a; dvr[d*3+x]=b;
    }
  }
}

// ---------------- CSR build ----------------
__global__ __launch_bounds__(256) void k_hist(const int* __restrict__ ei, int* __restrict__ deg){
  int e = blockIdx.x*256 + threadIdx.x;
  if (e >= EE) return;
  atomicAdd(deg + ei[EE + e], 1);
}

__global__ __launch_bounds__(1024) void k_scan(const int* __restrict__ deg,
                                               int* __restrict__ base, int* __restrict__ cursor){
  __shared__ int lds[1024];
  int t = threadIdx.x;
  int v[32];
#pragma unroll
  for (int i=0;i<32;++i) v[i] = deg[t*32+i];
  int run = 0;
#pragma unroll
  for (int i=0;i<32;++i){ int x=v[i]; v[i]=run; run+=x; }
  lds[t]=run; __syncthreads();
  for (int off=1; off<1024; off<<=1){
    int add = (t>=off) ? lds[t-off] : 0;
    __syncthreads();
    lds[t] += add;
    __syncthreads();
  }
  int pre = (t==0) ? 0 : lds[t-1];
#pragma unroll
  for (int i=0;i<32;++i){ int b = pre + v[i]; base[t*32+i]=b; cursor[t*32+i]=b; }
}

__global__ __launch_bounds__(256) void k_scatter(const int* __restrict__ ei,
                                                 int* __restrict__ cursor, int* __restrict__ csr){
  int e = blockIdx.x*256 + threadIdx.x;
  if (e >= EE) return;
  int d = ei[EE + e];
  int pos = atomicAdd(cursor + d, 1);
  csr[pos] = e;
}

// ============== cooperative edge pass A: attention logits ==================
#define A_RBFA 0
#define A_RBFD 640
#define A_WA   960
#define A_ADOT 4288
#define A_EDG  4352
#define A_ESTR 152

__global__ __launch_bounds__(512) void k_edgeA2(
    const int* __restrict__ ei,
    const float* __restrict__ rbf, const float* __restrict__ rsh,
    const float* __restrict__ Wrbf, const float* __restrict__ Wa,
    const float* __restrict__ adot,
    const float* __restrict__ ss, const float* __restrict__ ds,
    const float* __restrict__ sv, const float* __restrict__ dv,
    float* __restrict__ logits)
{
  __shared__ __align__(16) float SH[A_EDG + 16*A_ESTR];
  const int t = threadIdx.x;
  for (int i=t; i<32*16; i+=512){ int row=i>>4, j=i&15; SH[A_RBFA+row*20+j] = Wrbf[j*112+row]; }
  for (int i=t; i<16*16; i+=512){ int row=i>>4, j=i&15; SH[A_RBFD+row*20+j] = Wrbf[j*112+80+row]; }
  for (int i=t; i<64*48; i+=512){ int o=i/48, k=i-48*o; SH[A_WA+o*52+k] = Wa[k*64+o]; }
  for (int i=t; i<64;    i+=512){ SH[A_ADOT+i] = adot[i]; }
  __syncthreads();

  const int g = t >> 5;
  const int c = t & 31;
  float* E = &SH[A_EDG + g*A_ESTR];
  const float IS3 = 0.57735026918962576f;

#pragma unroll 1
  for (int tile=0; tile<16; ++tile){
    const int e = blockIdx.x*256 + tile*16 + g;
    const int src = ei[e], dst = ei[EE + e];

    if (c < 8){
      float4 a = *reinterpret_cast<const float4*>(ss + (size_t)src*32 + c*4);
      float4 b = *reinterpret_cast<const float4*>(ds + (size_t)dst*32 + c*4);
      float4 o; o.x=a.x+b.x; o.y=a.y+b.y; o.z=a.z+b.z; o.w=a.w+b.w;
      *reinterpret_cast<float4*>(&E[c*4]) = o;
    } else if (c < 20){
      int i = c-8;
      float4 a = *reinterpret_cast<const float4*>(sv + (size_t)src*48 + i*4);
      float4 b = *reinterpret_cast<const float4*>(dv + (size_t)dst*48 + i*4);
      float4 o; o.x=a.x+b.x; o.y=a.y+b.y; o.z=a.z+b.z; o.w=a.w+b.w;
      *reinterpret_cast<float4*>(&E[32+i*4]) = o;
    } else if (c < 24){
      int i = c-20;
      *reinterpret_cast<float4*>(&E[80+i*4]) =
          *reinterpret_cast<const float4*>(rbf + (size_t)e*16 + i*4);
    } else if (c == 24){
      *reinterpret_cast<float4*>(&E[96]) =
          *reinterpret_cast<const float4*>(rsh + (size_t)e*4);
    }

    float rr[16];
#pragma unroll
    for (int i=0;i<4;++i) *reinterpret_cast<float4*>(&rr[i*4]) =
        *reinterpret_cast<const float4*>(&E[80+i*4]);
    const float y0=E[96], y1x=E[97], y1y=E[98], y1z=E[99];
    {
      float wA=0.f;
#pragma unroll
      for (int j4=0;j4<4;++j4){
        float4 a0 = *reinterpret_cast<const float4*>(&SH[A_RBFA + c*20 + j4*4]);
        wA += rr[j4*4+0]*a0.x + rr[j4*4+1]*a0.y + rr[j4*4+2]*a0.z + rr[j4*4+3]*a0.w;
      }
      E[104+c] = wA * E[c] * y0;
    }
    if (c < 16){
      float wD=0.f;
#pragma unroll
      for (int j4=0;j4<4;++j4){
        float4 a0 = *reinterpret_cast<const float4*>(&SH[A_RBFD + c*20 + j4*4]);
        wD += rr[j4*4+0]*a0.x + rr[j4*4+1]*a0.y + rr[j4*4+2]*a0.z + rr[j4*4+3]*a0.w;
      }
      float vx=E[32+c*3], vy=E[33+c*3], vz=E[34+c*3];
      E[136+c] = wD * (vx*y1x + vy*y1y + vz*y1z) * IS3;
    }

    float mm[48];
#pragma unroll
    for (int k4=0;k4<12;++k4) *reinterpret_cast<float4*>(&mm[k4*4]) =
        *reinterpret_cast<const float4*>(&E[104+k4*4]);
    float acc0=0.f, acc1=0.f;
#pragma unroll
    for (int k4=0;k4<12;++k4){
      float4 w0 = *reinterpret_cast<const float4*>(&SH[A_WA + c*52 + k4*4]);
      float4 w1 = *reinterpret_cast<const float4*>(&SH[A_WA + (32+c)*52 + k4*4]);
      acc0 += mm[k4*4+0]*w0.x + mm[k4*4+1]*w0.y + mm[k4*4+2]*w0.z + mm[k4*4+3]*w0.w;
      acc1 += mm[k4*4+0]*w1.x + mm[k4*4+1]*w1.y + mm[k4*4+2]*w1.z + mm[k4*4+3]*w1.w;
    }
    acc0 = ((acc0 > 0.f) ? acc0 : 0.2f*acc0) * SH[A_ADOT+c];
    acc1 = ((acc1 > 0.f) ? acc1 : 0.2f*acc1) * SH[A_ADOT+32+c];
#pragma unroll
    for (int msk=8; msk>=1; msk>>=1){
      acc0 += __shfl_xor(acc0, msk);
      acc1 += __shfl_xor(acc1, msk);
    }
    if ((c & 15) == 0){
      int h0 = c >> 4;
      logits[(size_t)e*4 + h0]     = acc0;
      logits[(size_t)e*4 + 2 + h0] = acc1;
    }
  }
}

// ------------- per-(dst,head) softmax stats via CSR (no atomics) ----------
__global__ __launch_bounds__(256) void k_soft(
    const int* __restrict__ base, const int* __restrict__ deg,
    const int* __restrict__ csr, const float* __restrict__ logits,
    float* __restrict__ m, float* __restrict__ iden)
{
  int id = blockIdx.x*256 + threadIdx.x;
  if (id >= NN*4) return;
  int d = id >> 2, h = id & 3;
  int b = base[d], n = deg[d];
  float mm = -3.4e38f;
  for (int i=0;i<n;++i){ int e = csr[b+i]; mm = fmaxf(mm, logits[(size_t)e*4+h]); }
  float s = 0.f;
  for (int i=0;i<n;++i){ int e = csr[b+i]; s += __expf(logits[(size_t)e*4+h] - mm); }
  m[id] = mm;
  iden[id] = (n>0) ? 1.0f/s : 0.f;
}

// ============ edge value pass, part A: through SiLU/gating ================
// 8 groups x 32 lanes, 256 threads. LDS ~35.6 KB -> 3-4 blocks/CU.
// Writes 88 floats/edge into the FIRST 88 floats of the wflat row:
//   [0:32) vsg  [32:80) vvg(gated)  [80:84) alpha  [84:88) y
#define CA_RBF  0      // [112][20]
#define CA_VALS 2240   // [32][52]
#define CA_VVA  3904   // [16][36]
#define CA_VVB  4480   // [16][20]
#define CA_VVC  4800   // [16][20]
#define CA_G    5120   // [16][36]
#define CA_EDG  5696
#define CA_ESTR 400
// E: 0:s_[32] 32:v_[48] 80:r[16] 96:y[4] 100:a[4] 104:ms[48] 152:t_[32]
//    184:sa[16] 200:p[48] 248:q[48] 296:vs[32] 328:gv[16] 344:vv[48]

__global__ __launch_bounds__(256) void k_edgeCa(
    const int* __restrict__ csr, const int* __restrict__ ei,
    const float* __restrict__ rbf, const float* __restrict__ rsh,
    const float* __restrict__ Wrbf,
    const float* __restrict__ Wvals, const float* __restrict__ Wvalv,
    const float* __restrict__ Wg,
    const float* __restrict__ ss, const float* __restrict__ ds,
    const float* __restrict__ sv, const float* __restrict__ dv,
    const float* __restrict__ logits, const float* __restrict__ m,
    const float* __restrict__ iden, float* __restrict__ wflat)
{
  __shared__ __align__(16) float SH[CA_EDG + 8*CA_ESTR];
  const int t = threadIdx.x;
  for (int i=t; i<112*16; i+=256){ int d=i>>4, k=i&15; SH[CA_RBF+d*20+k]  = Wrbf[k*112+d]; }
  for (int i=t; i<32*48;  i+=256){ int d=i/48, k=i-48*d; SH[CA_VALS+d*52+k] = Wvals[k*32+d]; }
  for (int i=t; i<16*32;  i+=256){ int d=i>>5, k=i&31; SH[CA_VVA+d*36+k]  = Wvalv[k*16+d]; }
  for (int i=t; i<16*16;  i+=256){ int d=i>>4, k=i&15; SH[CA_VVB+d*20+k]  = Wvalv[(32+k)*16+d]; }
  for (int i=t; i<16*16;  i+=256){ int d=i>>4, k=i&15; SH[CA_VVC+d*20+k]  = Wvalv[(48+k)*16+d]; }
  for (int i=t; i<16*32;  i+=256){ int d=i>>5, k=i&31; SH[CA_G+d*36+k]    = Wg[k*16+d]; }
  __syncthreads();

  const int g = t >> 5;
  const int c = t & 31;
  float* E = &SH[CA_EDG + g*CA_ESTR];
  const float IS3 = 0.57735026918962576f;
  const float IS2 = 0.70710678118654752f;

#pragma unroll 1
  for (int tile=0; tile<16; ++tile){
    const int pidx = blockIdx.x*128 + tile*8 + g;
    const int e = csr[pidx];
    const int src = ei[e], dst = ei[EE + e];

    // phase 0: stage edge data
    if (c < 8){
      float4 a = *reinterpret_cast<const float4*>(ss + (size_t)src*32 + c*4);
      float4 b = *reinterpret_cast<const float4*>(ds + (size_t)dst*32 + c*4);
      float4 o; o.x=a.x+b.x; o.y=a.y+b.y; o.z=a.z+b.z; o.w=a.w+b.w;
      *reinterpret_cast<float4*>(&E[c*4]) = o;
    } else if (c < 20){
      int i = c-8;
      float4 a = *reinterpret_cast<const float4*>(sv + (size_t)src*48 + i*4);
      float4 b = *reinterpret_cast<const float4*>(dv + (size_t)dst*48 + i*4);
      float4 o; o.x=a.x+b.x; o.y=a.y+b.y; o.z=a.z+b.z; o.w=a.w+b.w;
      *reinterpret_cast<float4*>(&E[32+i*4]) = o;
    } else if (c < 24){
      int i = c-20;
      *reinterpret_cast<float4*>(&E[80+i*4]) =
          *reinterpret_cast<const float4*>(rbf + (size_t)e*16 + i*4);
    } else if (c == 24){
      *reinterpret_cast<float4*>(&E[96]) =
          *reinterpret_cast<const float4*>(rsh + (size_t)e*4);
    } else if (c == 25){
      float4 l4 = *reinterpret_cast<const float4*>(logits + (size_t)e*4);
      float4 m4 = *reinterpret_cast<const float4*>(m + (size_t)dst*4);
      float4 i4 = *reinterpret_cast<const float4*>(iden + (size_t)dst*4);
      E[100] = __expf(l4.x-m4.x)*i4.x;
      E[101] = __expf(l4.y-m4.y)*i4.y;
      E[102] = __expf(l4.z-m4.z)*i4.z;
      E[103] = __expf(l4.w-m4.w)*i4.w;
    }

    // phase 1: w channels
    float rr[16];
#pragma unroll
    for (int i=0;i<4;++i) *reinterpret_cast<float4*>(&rr[i*4]) =
        *reinterpret_cast<const float4*>(&E[80+i*4]);
    float wA=0.f, wB=0.f, wC=0.f, wD=0.f;
#pragma unroll
    for (int j4=0;j4<4;++j4){
      float4 a0 = *reinterpret_cast<const float4*>(&SH[CA_RBF + c*20           + j4*4]);
      float4 a1 = *reinterpret_cast<const float4*>(&SH[CA_RBF + (32+c)*20      + j4*4]);
      float4 a2 = *reinterpret_cast<const float4*>(&SH[CA_RBF + (64+c)*20      + j4*4]);
      float4 a3 = *reinterpret_cast<const float4*>(&SH[CA_RBF + (96+(c&15))*20 + j4*4]);
      float r0=rr[j4*4+0], r1=rr[j4*4+1], r2=rr[j4*4+2], r3=rr[j4*4+3];
      wA += r0*a0.x + r1*a0.y + r2*a0.z + r3*a0.w;
      wB += r0*a1.x + r1*a1.y + r2*a1.z + r3*a1.w;
      wC += r0*a2.x + r1*a2.y + r2*a2.z + r3*a2.w;
      wD += r0*a3.x + r1*a3.y + r2*a3.z + r3*a3.w;
    }

    // phase 2: ms, t_, p, q
    const float y0=E[96], y1x=E[97], y1y=E[98], y1z=E[99];
    const float s_c = E[c];
    E[104+c] = wA * s_c * y0;
    E[152+c] = wB * s_c;
    if (c >= 16){
      int k = c-16;
      float vx=E[32+k*3], vy=E[33+k*3], vz=E[34+k*3];
      E[136+k] = wC * (vx*y1x+vy*y1y+vz*y1z) * IS3;
    }
    if (c < 16){
      int k = c;
      float vx=E[32+k*3], vy=E[33+k*3], vz=E[34+k*3];
      float u = wC * y0;
      E[200+k]    = u*vx; E[216+k] = u*vy; E[232+k] = u*vz;
      float cx=(vy*y1z - vz*y1y)*IS2;
      float cy=(vz*y1x - vx*y1z)*IS2;
      float cz=(vx*y1y - vy*y1x)*IS2;
      E[248+k]    = wD*cx; E[264+k] = wD*cy; E[280+k] = wD*cz;
    }

    // phase 3: sa[16] = t_ @ WvalvA
    if (c < 16){
      float acc=0.f, accB=0.f;
#pragma unroll
      for (int k4=0;k4<8;k4+=2){
        float4 w0 = *reinterpret_cast<const float4*>(&SH[CA_VVA + c*36 + k4*4]);
        float4 t0 = *reinterpret_cast<const float4*>(&E[152+k4*4]);
        float4 w1 = *reinterpret_cast<const float4*>(&SH[CA_VVA + c*36 + k4*4+4]);
        float4 t1 = *reinterpret_cast<const float4*>(&E[152+k4*4+4]);
        acc  += w0.x*t0.x + w0.y*t0.y + w0.z*t0.z + w0.w*t0.w;
        accB += w1.x*t1.x + w1.y*t1.y + w1.z*t1.z + w1.w*t1.w;
      }
      E[184+c]=acc+accB;
    }

    // phase 4: vv (ungated)
    {
      int d0=c/3, x0=c-3*d0;
      float acc0 = E[184+d0]*E[97+x0];
#pragma unroll
      for (int k4=0;k4<4;++k4){
        float4 wb = *reinterpret_cast<const float4*>(&SH[CA_VVB + d0*20 + k4*4]);
        float4 wc = *reinterpret_cast<const float4*>(&SH[CA_VVC + d0*20 + k4*4]);
        float4 pp = *reinterpret_cast<const float4*>(&E[200 + x0*16 + k4*4]);
        float4 qq = *reinterpret_cast<const float4*>(&E[248 + x0*16 + k4*4]);
        acc0 += pp.x*wb.x+pp.y*wb.y+pp.z*wb.z+pp.w*wb.w
              + qq.x*wc.x+qq.y*wc.y+qq.z*wc.z+qq.w*wc.w;
      }
      E[344+c]=acc0;
      if (c < 16){
        int l=32+c, d1=l/3, x1=l-3*d1;
        float acc1 = E[184+d1]*E[97+x1];
#pragma unroll
        for (int k4=0;k4<4;++k4){
          float4 wb = *reinterpret_cast<const float4*>(&SH[CA_VVB + d1*20 + k4*4]);
          float4 wc = *reinterpret_cast<const float4*>(&SH[CA_VVC + d1*20 + k4*4]);
          float4 pp = *reinterpret_cast<const float4*>(&E[200 + x1*16 + k4*4]);
          float4 qq = *reinterpret_cast<const float4*>(&E[248 + x1*16 + k4*4]);
          acc1 += pp.x*wb.x+pp.y*wb.y+pp.z*wb.z+pp.w*wb.w
                + qq.x*wc.x+qq.y*wc.y+qq.z*wc.z+qq.w*wc.w;
        }
        E[344+l]=acc1;
      }
    }

    // phase 5: vs[32] = ms @ Wvals (dual accumulators)
    float accv=0.f, accw=0.f;
#pragma unroll
    for (int k4=0;k4<12;k4+=2){
      float4 w0 = *reinterpret_cast<const float4*>(&SH[CA_VALS + c*52 + k4*4]);
      float4 m0 = *reinterpret_cast<const float4*>(&E[104+k4*4]);
      float4 w1 = *reinterpret_cast<const float4*>(&SH[CA_VALS + c*52 + k4*4+4]);
      float4 m1 = *reinterpret_cast<const float4*>(&E[104+k4*4+4]);
      accv += w0.x*m0.x + w0.y*m0.y + w0.z*m0.z + w0.w*m0.w;
      accw += w1.x*m1.x + w1.y*m1.y + w1.z*m1.z + w1.w*m1.w;
    }
    accv += accw;
    E[296+c]=accv;

    // phase 6: gv[16]
    if (c < 16){
      float acc=0.f;
#pragma unroll
      for (int k4=0;k4<8;++k4){
        float4 ww = *reinterpret_cast<const float4*>(&SH[CA_G + c*36 + k4*4]);
        float4 vv4 = *reinterpret_cast<const float4*>(&E[296+k4*4]);
        acc += ww.x*vv4.x + ww.y*vv4.y + ww.z*vv4.z + ww.w*vv4.w;
      }
      E[328+c]=sigm(acc);
    }

    // phase 7: silu + gate, stream 88 floats to wflat row head
    float* erow = wflat + (size_t)pidx*160;
    erow[c] = accv * sigm(accv);                 // vsg
    erow[32+c] = E[344+c]*E[328+c/3];            // vvg[0:32)
    if (c < 16){
      int l = 32+c;
      erow[64+c] = E[344+l]*E[328+l/3];          // vvg[32:48)
    }
    if (c < 8){
      erow[80+c] = (c<4) ? E[100+c] : E[96+c-4]; // alpha[4], y[4]
    }
  }
}

// ============ edge value pass, part B: second CG + projections ============
// Reads the 88-float head of each wflat row, overwrites the row with the
// final 160-float weighted output. Safe: each group's wave reads its own
// row before (program order) it writes that row.
#define CB_VLS  0      // [64][52]
#define CB_VLVA 3328   // [32][36]
#define CB_VLVB 4480   // [32][20]
#define CB_VLVC 5120   // [32][20]
#define CB_W2   5760   // [112]
#define CB_EDG  5872
#define CB_ESTR 240
// E: 0:vvg[48] 48:a[4] 52:y[4] 56:vs2[48] 104:t2[32]
//    136:p2x[16] 152:p2y 168:p2z 184:q2x 200:q2y 216:q2z

__global__ __launch_bounds__(256) void k_edgeCb(
    const float* __restrict__ Wvls, const float* __restrict__ Wvlv,
    const float* __restrict__ w2, float* __restrict__ wflat)
{
  __shared__ __align__(16) float SH[CB_EDG + 8*CB_ESTR];
  const int t = threadIdx.x;
  for (int i=t; i<64*48; i+=256){ int d=i/48, k=i-48*d; SH[CB_VLS+d*52+k] = Wvls[k*64+d]; }
  for (int i=t; i<32*32; i+=256){ int d=i>>5, k=i&31; SH[CB_VLVA+d*36+k] = Wvlv[k*32+d]; }
  for (int i=t; i<32*16; i+=256){ int d=i>>4, k=i&15; SH[CB_VLVB+d*20+k] = Wvlv[(32+k)*32+d]; }
  for (int i=t; i<32*16; i+=256){ int d=i>>4, k=i&15; SH[CB_VLVC+d*20+k] = Wvlv[(48+k)*32+d]; }
  for (int i=t; i<112;   i+=256){ SH[CB_W2+i] = w2[i]; }
  __syncthreads();

  const int g = t >> 5;
  const int c = t & 31;
  float* E = &SH[CB_EDG + g*CB_ESTR];
  const float IS3 = 0.57735026918962576f;
  const float IS2 = 0.70710678118654752f;

#pragma unroll 1
  for (int tile=0; tile<16; ++tile){
    const int pidx = blockIdx.x*128 + tile*8 + g;
    float* wrow = wflat + (size_t)pidx*160;

    // stage: vsg to register, vvg/a/y to LDS
    const float vsc = wrow[c];
    E[c] = wrow[32+c];
    if (c < 16) E[32+c] = wrow[64+c];
    if (c < 8)  E[48+c] = wrow[80+c];

    const float y0=E[52], y1x=E[53], y1y=E[54], y1z=E[55];

    // elementwise: t2, vs2, p2, q2
    E[104+c] = SH[CB_W2+32+c]*vsc;
    E[56+c]  = SH[CB_W2+c]*vsc*y0;
    if (c >= 16){
      int k = c-16;
      float gx=E[k*3], gy=E[k*3+1], gz=E[k*3+2];
      E[88+k] = SH[CB_W2+80+k]*(gx*y1x+gy*y1y+gz*y1z)*IS3;
    }
    if (c < 16){
      int k = c;
      float gx=E[k*3], gy=E[k*3+1], gz=E[k*3+2];
      float u = SH[CB_W2+64+k]*y0;
      E[136+k]=u*gx; E[152+k]=u*gy; E[168+k]=u*gz;
      float cx=(gy*y1z - gz*y1y)*IS2;
      float cy=(gz*y1x - gx*y1z)*IS2;
      float cz=(gx*y1y - gy*y1x)*IS2;
      float wq = SH[CB_W2+96+k];
      E[184+k]=wq*cx; E[200+k]=wq*cy; E[216+k]=wq*cz;
    }

    const float a0=E[48], a1=E[49], a2h=E[50], a3h=E[51];

    // flat_s[64] = vs2 @ Wvls (dual accumulators)
    {
      float f0a=0.f, f0b=0.f, f1a=0.f, f1b=0.f;
#pragma unroll
      for (int k4=0;k4<12;k4+=2){
        float4 v0 = *reinterpret_cast<const float4*>(&E[56+k4*4]);
        float4 v1 = *reinterpret_cast<const float4*>(&E[56+k4*4+4]);
        float4 wa0 = *reinterpret_cast<const float4*>(&SH[CB_VLS + c*52 + k4*4]);
        float4 wa1 = *reinterpret_cast<const float4*>(&SH[CB_VLS + c*52 + k4*4+4]);
        float4 wb0 = *reinterpret_cast<const float4*>(&SH[CB_VLS + (32+c)*52 + k4*4]);
        float4 wb1 = *reinterpret_cast<const float4*>(&SH[CB_VLS + (32+c)*52 + k4*4+4]);
        f0a += v0.x*wa0.x + v0.y*wa0.y + v0.z*wa0.z + v0.w*wa0.w;
        f0b += v1.x*wa1.x + v1.y*wa1.y + v1.z*wa1.z + v1.w*wa1.w;
        f1a += v0.x*wb0.x + v0.y*wb0.y + v0.z*wb0.z + v0.w*wb0.w;
        f1b += v1.x*wb1.x + v1.y*wb1.y + v1.z*wb1.z + v1.w*wb1.w;
      }
      wrow[c]    = (f0a+f0b)*a0;
      wrow[32+c] = (f1a+f1b)*((c<8)?a0:a1);
    }

    // flat_v[96]
    {
      float A2=0.f, A2b=0.f;
#pragma unroll
      for (int k4=0;k4<8;k4+=2){
        float4 w0 = *reinterpret_cast<const float4*>(&SH[CB_VLVA + c*36 + k4*4]);
        float4 t0 = *reinterpret_cast<const float4*>(&E[104+k4*4]);
        float4 w1 = *reinterpret_cast<const float4*>(&SH[CB_VLVA + c*36 + k4*4+4]);
        float4 t1 = *reinterpret_cast<const float4*>(&E[104+k4*4+4]);
        A2  += w0.x*t0.x + w0.y*t0.y + w0.z*t0.z + w0.w*t0.w;
        A2b += w1.x*t1.x + w1.y*t1.y + w1.z*t1.z + w1.w*t1.w;
      }
      A2 += A2b;
      float b0=A2*y1x, b1=A2*y1y, b2=A2*y1z;
#pragma unroll
      for (int k4=0;k4<4;++k4){
        float4 wb = *reinterpret_cast<const float4*>(&SH[CB_VLVB + c*20 + k4*4]);
        float4 wc = *reinterpret_cast<const float4*>(&SH[CB_VLVC + c*20 + k4*4]);
        float4 p0 = *reinterpret_cast<const float4*>(&E[136 + k4*4]);
        float4 p1 = *reinterpret_cast<const float4*>(&E[152 + k4*4]);
        float4 p2v= *reinterpret_cast<const float4*>(&E[168 + k4*4]);
        float4 q0 = *reinterpret_cast<const float4*>(&E[184 + k4*4]);
        float4 q1 = *reinterpret_cast<const float4*>(&E[200 + k4*4]);
        float4 q2v= *reinterpret_cast<const float4*>(&E[216 + k4*4]);
        b0 += p0.x*wb.x+p0.y*wb.y+p0.z*wb.z+p0.w*wb.w + q0.x*wc.x+q0.y*wc.y+q0.z*wc.z+q0.w*wc.w;
        b1 += p1.x*wb.x+p1.y*wb.y+p1.z*wb.z+p1.w*wb.w + q1.x*wc.x+q1.y*wc.y+q1.z*wc.z+q1.w*wc.w;
        b2 += p2v.x*wb.x+p2v.y*wb.y+p2v.z*wb.z+p2v.w*wb.w + q2v.x*wc.x+q2v.y*wc.y+q2v.z*wc.z+q2v.w*wc.w;
      }
      int o = 64 + c*3;
      float aw0 = (o   < 80) ? a1 : ((o   < 120) ? a2h : a3h);
      float aw1 = (o+1 < 80) ? a1 : ((o+1 < 120) ? a2h : a3h);
      float aw2 = (o+2 < 80) ? a1 : ((o+2 < 120) ? a2h : a3h);
      wrow[o]   = b0*aw0;
      wrow[o+1] = b1*aw1;
      wrow[o+2] = b2*aw2;
    }
  }
}

// ------------- gather: per-dst sum of weighted per-edge rows ---------------
__global__ __launch_bounds__(256) void k_gather(
    const int* __restrict__ base, const int* __restrict__ deg,
    const float* __restrict__ wflat, float* __restrict__ agg)
{
  int id = blockIdx.x*256 + threadIdx.x;
  if (id >= NN*40) return;
  int d = id / 40, c = id % 40;
  int b = base[d], n = deg[d];
  float4 acc = make_float4(0.f,0.f,0.f,0.f);
  for (int i=0;i<n;++i){
    float4 w = reinterpret_cast<const float4*>(wflat + (size_t)(b+i)*160)[c];
    acc.x += w.x; acc.y += w.y; acc.z += w.z; acc.w += w.w;
  }
  reinterpret_cast<float4*>(agg + (size_t)d*160)[c] = acc;
}

// ------------- output pass: Wp projections + residual ----------------------
__global__ __launch_bounds__(256) void k_out(
    const float* __restrict__ node, const float* __restrict__ agg,
    const float* __restrict__ Wps, const float* __restrict__ Wpv,
    float* __restrict__ out)
{
  int n = blockIdx.x * 256 + threadIdx.x;
  if (n >= NN) return;
  const float* ar = agg + (size_t)n*160;
  const float* nr = node + (size_t)n*80;
  float* orow = out + (size_t)n*80;

  float a[64];
  { const float4* ap = reinterpret_cast<const float4*>(ar);
#pragma unroll
    for (int i=0;i<16;++i){ float4 t=ap[i];
      a[i*4]=t.x; a[i*4+1]=t.y; a[i*4+2]=t.z; a[i*4+3]=t.w; } }
#pragma unroll 1
  for (int d=0; d<32; ++d){
    float acc=0.f;
#pragma unroll
    for (int c=0;c<64;++c) acc += a[c]*Wps[c*32+d];
    orow[d] = nr[d] + acc;
  }
  float b[96];
  { const float4* bp = reinterpret_cast<const float4*>(ar + 64);
#pragma unroll
    for (int i=0;i<24;++i){ float4 t=bp[i];
      b[i*4]=t.x; b[i*4+1]=t.y; b[i*4+2]=t.z; b[i*4+3]=t.w; } }
#pragma unroll 1
  for (int d=0; d<16; ++d){
#pragma unroll
    for (int x=0;x<3;++x){
      float acc=0.f;
#pragma unroll
      for (int c=0;c<32;++c) acc += b[c*3+x]*Wpv[c*16+d];
      orow[32+d*3+x] = nr[32+d*3+x] + acc;
    }
  }
}

extern "C" void kernel_launch(void* const* d_in, const int* in_sizes, int n_in,
                              void* d_out, int out_size, void* d_ws, size_t ws_size,
                              hipStream_t stream)
{
  const float* node   = (const float*)d_in[0];
  const float* rbf    = (const float*)d_in[1];
  const float* rsh    = (const float*)d_in[2];
  const float* Wsrc_s = (const float*)d_in[3];
  const float* Wsrc_v = (const float*)d_in[4];
  const float* Wdst_s = (const float*)d_in[5];
  const float* Wdst_v = (const float*)d_in[6];
  const float* W_rbf  = (const float*)d_in[7];
  const float* dtp2   = (const float*)d_in[8];
  const float* Wa     = (const float*)d_in[9];
  const float* adot   = (const float*)d_in[10];
  const float* Wval_s = (const float*)d_in[11];
  const float* Wval_v = (const float*)d_in[12];
  const float* Wg     = (const float*)d_in[13];
  const float* Wvl_s  = (const float*)d_in[14];
  const float* Wvl_v  = (const float*)d_in[15];
  const float* Wp_s   = (const float*)d_in[16];
  const float* Wp_v   = (const float*)d_in[17];
  const int*   ei     = (const int*)d_in[18];

  float* ws = (float*)d_ws;

  size_t off = 0;
  float* ss   = ws + off; off += (size_t)NN*32;
  float* ds   = ws + off; off += (size_t)NN*32;
  float* sv   = ws + off; off += (size_t)NN*48;
  float* dv   = ws + off; off += (size_t)NN*48;
  float* lg   = ws + off; off += (size_t)EE*4;
  float* m    = ws + off; off += (size_t)NN*4;
  float* iden = ws + off; off += (size_t)NN*4;
  int* deg    = (int*)(ws + off); off += (size_t)NN;
  int* base   = (int*)(ws + off); off += (size_t)NN;
  int* cursor = (int*)(ws + off); off += (size_t)NN;
  int* csr    = (int*)(ws + off); off += (size_t)EE;
  float* agg  = ws + off; off += (size_t)NN*160;
  float* wflat= ws + off; off += (size_t)EE*160;
  size_t need_new = off * sizeof(float);
  if (ws_size < need_new) return;

  hipMemsetAsync(deg, 0, (size_t)NN*sizeof(int), stream);
  k_node   <<<NN/256, 256, 0, stream>>>(node, Wsrc_s, Wsrc_v, Wdst_s, Wdst_v, ss, ds, sv, dv);
  k_hist   <<<EE/256, 256, 0, stream>>>(ei, deg);
  k_scan   <<<1, 1024, 0, stream>>>(deg, base, cursor);
  k_scatter<<<EE/256, 256, 0, stream>>>(ei, cursor, csr);
  k_edgeA2 <<<EE/256, 512, 0, stream>>>(ei, rbf, rsh, W_rbf, Wa, adot, ss, ds, sv, dv, lg);
  k_soft   <<<(NN*4)/256, 256, 0, stream>>>(base, deg, csr, lg, m, iden);
  k_edgeCa <<<EE/128, 256, 0, stream>>>(csr, ei, rbf, rsh, W_rbf, Wval_s, Wval_v, Wg,
                                        ss, ds, sv, dv, lg, m, iden, wflat);
  k_edgeCb <<<EE/128, 256, 0, stream>>>(Wvl_s, Wvl_v, dtp2, wflat);
  k_gather <<<(NN*40)/256, 256, 0, stream>>>(base, deg, wflat, agg);
  k_out    <<<NN/256, 256, 0, stream>>>(node, agg, Wp_s, Wp_v, (float*)d_out);
}